// Round 1
// baseline (5522.772 us; speedup 1.0000x reference)
//
#include <hip/hip_runtime.h>
#include <math.h>

#define D_MODEL 1024
#define D_FF    4096
#define NE      8
#define NTOK    4096   // 2*2048
#define TM      32     // tokens per FFN block
#define FFC     128    // ff chunk
#define KSTEP   64     // k sub-chunk
#define MAXTOK  4096   // worst-case tokens per expert

// ---------------- gating: logits -> top2 -> renorm weights -> route ----------------
__global__ __launch_bounds__(256) void gating_kernel(
    const float* __restrict__ x, const float* __restrict__ Wg, const float* __restrict__ bg,
    int* __restrict__ cnt, int* __restrict__ tok_ids, float* __restrict__ tok_w)
{
    __shared__ float s_wg[D_MODEL * NE];  // 32 KB
    int tid = threadIdx.x;
    for (int i = tid; i < D_MODEL * NE; i += 256) s_wg[i] = Wg[i];
    __syncthreads();

    int t = blockIdx.x * 256 + tid;  // grid is exactly 16*256 = 4096
    float acc[NE];
    #pragma unroll
    for (int e = 0; e < NE; ++e) acc[e] = bg[e];
    const float* xr = x + (size_t)t * D_MODEL;
    for (int d = 0; d < D_MODEL; ++d) {
        float xv = xr[d];
        #pragma unroll
        for (int e = 0; e < NE; ++e) acc[e] += xv * s_wg[d * NE + e];
    }
    // top-2 (ties -> lower index, matches jax.lax.top_k)
    int i0 = 0;
    #pragma unroll
    for (int e = 1; e < NE; ++e) if (acc[e] > acc[i0]) i0 = e;
    int i1 = (i0 == 0) ? 1 : 0;
    #pragma unroll
    for (int e = 0; e < NE; ++e) if (e != i0 && acc[e] > acc[i1]) i1 = e;
    // renormalized top-2 softmax weights: softmax denom cancels
    float e1 = __expf(acc[i1] - acc[i0]);
    float inv = 1.0f / (1.0f + e1);
    float w0 = inv, w1 = e1 * inv;

    int p0 = atomicAdd(&cnt[i0], 1);
    tok_ids[i0 * MAXTOK + p0] = t;  tok_w[i0 * MAXTOK + p0] = w0;
    int p1 = atomicAdd(&cnt[i1], 1);
    tok_ids[i1 * MAXTOK + p1] = t;  tok_w[i1 * MAXTOK + p1] = w1;
}

// ---------------- fused FFN: h = gelu(Xg @ W1 + b1); out += w * (h @ W2 + b2) ----------------
// block: 512 threads. blockIdx.y = expert, blockIdx.x = token tile, blockIdx.z = ff half.
__global__ __launch_bounds__(512) void ffn_kernel(
    const float* __restrict__ x,
    const float* __restrict__ W1, const float* __restrict__ b1,
    const float* __restrict__ W2, const float* __restrict__ b2,
    const int* __restrict__ cnt, const int* __restrict__ tok_ids, const float* __restrict__ tok_w,
    float* __restrict__ out)
{
    int e = blockIdx.y;
    int n = cnt[e];
    int t0 = blockIdx.x * TM;
    if (t0 >= n) return;
    int tid = threadIdx.x;

    __shared__ int   s_tok[TM];
    __shared__ float s_w[TM];
    __shared__ float s_x[TM][KSTEP];    // 8 KB
    __shared__ float s_w1[KSTEP][FFC];  // 32 KB
    __shared__ float s_h[TM][FFC];      // 16 KB

    if (tid < TM) {
        int idx = t0 + tid;
        s_tok[tid] = (idx < n) ? tok_ids[e * MAXTOK + idx] : -1;
        s_w[tid]   = (idx < n) ? tok_w[e * MAXTOK + idx] : 0.0f;
    }
    __syncthreads();

    // per-thread output accumulators: 32 tokens x 2 cols (col = tid, tid+512)
    float acc[TM][2];
    #pragma unroll
    for (int i = 0; i < TM; ++i) { acc[i][0] = 0.0f; acc[i][1] = 0.0f; }

    const float* W1e = W1 + (size_t)e * D_MODEL * D_FF;
    const float* W2e = W2 + (size_t)e * D_FF * D_MODEL;
    const float* b1e = b1 + (size_t)e * D_FF;

    // phase-A thread mapping: ff pair + token group (g uniform per wave -> s_x reads broadcast)
    int ffl = (tid & 63) * 2;
    int g   = tid >> 6;  // 0..7 -> tokens g*4..g*4+3

    int fb0 = blockIdx.z * (D_FF / 2);
    for (int fb = fb0; fb < fb0 + D_FF / 2; fb += FFC) {
        float bv0 = b1e[fb + ffl], bv1 = b1e[fb + ffl + 1];
        float hacc[4][2];
        #pragma unroll
        for (int j = 0; j < 4; ++j) { hacc[j][0] = bv0; hacc[j][1] = bv1; }

        for (int kb = 0; kb < D_MODEL; kb += KSTEP) {
            // stage x tile: 32x64 floats, 4 per thread, coalesced
            #pragma unroll
            for (int r = 0; r < 4; ++r) {
                int i = tid + 512 * r;
                int row = i >> 6, col = i & 63;
                int tok = s_tok[row];
                s_x[row][col] = (tok >= 0) ? x[(size_t)tok * D_MODEL + kb + col] : 0.0f;
            }
            // stage W1 tile: 64x128 floats, 16 per thread, coalesced
            #pragma unroll
            for (int r = 0; r < 16; ++r) {
                int i = tid + 512 * r;
                int row = i >> 7, col = i & 127;
                s_w1[row][col] = W1e[(size_t)(kb + row) * D_FF + fb + col];
            }
            __syncthreads();
            #pragma unroll 8
            for (int kk = 0; kk < KSTEP; ++kk) {
                float2 wv = *reinterpret_cast<const float2*>(&s_w1[kk][ffl]);
                #pragma unroll
                for (int j = 0; j < 4; ++j) {
                    float xv = s_x[g * 4 + j][kk];
                    hacc[j][0] += xv * wv.x;
                    hacc[j][1] += xv * wv.y;
                }
            }
            __syncthreads();
        }
        // exact GELU, store h tile
        #pragma unroll
        for (int j = 0; j < 4; ++j) {
            #pragma unroll
            for (int p = 0; p < 2; ++p) {
                float v = hacc[j][p];
                v = 0.5f * v * (1.0f + erff(v * 0.70710678118654752f));
                s_h[g * 4 + j][ffl + p] = v;
            }
        }
        __syncthreads();
        // phase B: out_acc += h(32xFFC) @ W2chunk(FFCx1024); W2 streamed, h broadcast from LDS
        for (int ff = 0; ff < FFC; ++ff) {
            const float* w2row = W2e + (size_t)(fb + ff) * D_MODEL;
            float wc0 = w2row[tid], wc1 = w2row[tid + 512];
            #pragma unroll
            for (int tt = 0; tt < TM; ++tt) {
                float hv = s_h[tt][ff];
                acc[tt][0] += hv * wc0;
                acc[tt][1] += hv * wc1;
            }
        }
        __syncthreads();
    }

    // epilogue: out[token] += gate_w * (acc + b2)   (b2 added only by z==0 half)
    float bc0 = b2[(size_t)e * D_MODEL + tid];
    float bc1 = b2[(size_t)e * D_MODEL + tid + 512];
    if (blockIdx.z != 0) { bc0 = 0.0f; bc1 = 0.0f; }
    #pragma unroll
    for (int tt = 0; tt < TM; ++tt) {
        int tok = s_tok[tt];
        if (tok >= 0) {
            float w = s_w[tt];
            atomicAdd(&out[(size_t)tok * D_MODEL + tid],       w * (acc[tt][0] + bc0));
            atomicAdd(&out[(size_t)tok * D_MODEL + tid + 512], w * (acc[tt][1] + bc1));
        }
    }
}

extern "C" void kernel_launch(void* const* d_in, const int* in_sizes, int n_in,
                              void* d_out, int out_size, void* d_ws, size_t ws_size,
                              hipStream_t stream) {
    const float* x  = (const float*)d_in[0];
    const float* Wg = (const float*)d_in[1];
    const float* bg = (const float*)d_in[2];
    const float* W1 = (const float*)d_in[3];
    const float* b1 = (const float*)d_in[4];
    const float* W2 = (const float*)d_in[5];
    const float* b2 = (const float*)d_in[6];
    float* out = (float*)d_out;

    // workspace layout
    int*   cnt     = (int*)d_ws;                          // 8 ints
    int*   tok_ids = (int*)((char*)d_ws + 256);           // 8*4096 ints
    float* tok_w   = (float*)((char*)d_ws + 256 + MAXTOK * NE * sizeof(int));

    hipMemsetAsync(cnt, 0, NE * sizeof(int), stream);
    hipMemsetAsync(out, 0, (size_t)out_size * sizeof(float), stream);

    gating_kernel<<<NTOK / 256, 256, 0, stream>>>(x, Wg, bg, cnt, tok_ids, tok_w);

    dim3 grid(MAXTOK / TM, NE, 2);
    ffn_kernel<<<grid, 512, 0, stream>>>(x, W1, b1, W2, b2, cnt, tok_ids, tok_w, out);
}

// Round 2
// 974.876 us; speedup vs baseline: 5.6651x; 5.6651x over previous
//
#include <hip/hip_runtime.h>
#include <hip/hip_bf16.h>
#include <math.h>

#define D_MODEL 1024
#define D_FF    4096
#define NE      8
#define NTOK    4096   // 2*2048
#define MAXTOK  4096
#define MAXROWS 9216   // 8192 slots + 8*128 padding worst case

typedef __attribute__((ext_vector_type(8))) short short8;
typedef __attribute__((ext_vector_type(4))) float f32x4;

// ---- workspace layout (bytes) ----
#define WS_CNT     0
#define WS_OFFA    128
#define WS_TOKIDS  1024
#define WS_TOKW    (WS_TOKIDS + NE*MAXTOK*4)          // 132096
#define WS_ROWTOK  (WS_TOKW + NE*MAXTOK*4)            // 263168
#define WS_ROWW    (WS_ROWTOK + MAXROWS*4)            // 300032
#define WS_XG      524288
#define WS_H       (WS_XG + (size_t)MAXROWS*D_MODEL*2)        // +18.9MB
#define WS_W1T     (WS_H + (size_t)MAXROWS*D_FF*2)            // +75.5MB
#define WS_W2T     (WS_W1T + (size_t)NE*D_MODEL*D_FF*2)       // +67.1MB
#define WS_NEED    (WS_W2T + (size_t)NE*D_MODEL*D_FF*2)       // ~218.5MB

__device__ __forceinline__ ushort f2b(float v) {
    __hip_bfloat16 b = __float2bfloat16(v);
    return *reinterpret_cast<ushort*>(&b);
}

// ---------------- gating: logits -> top2 -> renorm weights -> route ----------------
__global__ __launch_bounds__(256) void gating_kernel(
    const float* __restrict__ x, const float* __restrict__ Wg, const float* __restrict__ bg,
    int* __restrict__ cnt, int* __restrict__ tok_ids, float* __restrict__ tok_w)
{
    __shared__ float s_wg[D_MODEL * NE];  // 32 KB
    int tid = threadIdx.x;
    for (int i = tid; i < D_MODEL * NE; i += 256) s_wg[i] = Wg[i];
    __syncthreads();

    int t = blockIdx.x * 256 + tid;
    float acc[NE];
    #pragma unroll
    for (int e = 0; e < NE; ++e) acc[e] = bg[e];
    const float* xr = x + (size_t)t * D_MODEL;
    for (int d = 0; d < D_MODEL; ++d) {
        float xv = xr[d];
        #pragma unroll
        for (int e = 0; e < NE; ++e) acc[e] += xv * s_wg[d * NE + e];
    }
    int i0 = 0;
    #pragma unroll
    for (int e = 1; e < NE; ++e) if (acc[e] > acc[i0]) i0 = e;
    int i1 = (i0 == 0) ? 1 : 0;
    #pragma unroll
    for (int e = 0; e < NE; ++e) if (e != i0 && acc[e] > acc[i1]) i1 = e;
    float e1 = __expf(acc[i1] - acc[i0]);
    float inv = 1.0f / (1.0f + e1);
    float w0 = inv, w1 = e1 * inv;

    int p0 = atomicAdd(&cnt[i0], 1);
    tok_ids[i0 * MAXTOK + p0] = t;  tok_w[i0 * MAXTOK + p0] = w0;
    int p1 = atomicAdd(&cnt[i1], 1);
    tok_ids[i1 * MAXTOK + p1] = t;  tok_w[i1 * MAXTOK + p1] = w1;
}

// ---------------- scan: 128-aligned per-expert row offsets ----------------
__global__ void scan_kernel(const int* __restrict__ cnt, int* __restrict__ off) {
    if (threadIdx.x == 0) {
        int acc = 0;
        for (int e = 0; e < NE; ++e) { off[e] = acc; acc += ((cnt[e] + 127) & ~127); }
        off[NE] = acc;
    }
}

// ---------------- gather: x rows -> compact bf16 Xg (16B-slot swizzled) ----------------
__global__ __launch_bounds__(256) void gather_kernel(
    const float* __restrict__ x, const int* __restrict__ cnt, const int* __restrict__ off,
    const int* __restrict__ tok_ids, const float* __restrict__ tok_w,
    ushort* __restrict__ Xg, int* __restrict__ rowtok, float* __restrict__ roww)
{
    int e = blockIdx.y;
    int npad = off[e + 1] - off[e];
    int r0 = blockIdx.x * 128;
    if (r0 >= npad) return;
    int n = cnt[e];
    int base = off[e];
    for (int idx = threadIdx.x; idx < 128 * 128; idx += 256) {
        int r = r0 + (idx >> 7);
        int s = idx & 127;           // 16B slot within row (8 bf16)
        int R = base + r;
        int tok = -1;
        float4 v0 = {0, 0, 0, 0}, v1 = {0, 0, 0, 0};
        if (r < n) {
            tok = tok_ids[e * MAXTOK + r];
            const float4* src = (const float4*)(x + (size_t)tok * D_MODEL + s * 8);
            v0 = src[0]; v1 = src[1];
        }
        ushort o[8];
        o[0] = f2b(v0.x); o[1] = f2b(v0.y); o[2] = f2b(v0.z); o[3] = f2b(v0.w);
        o[4] = f2b(v1.x); o[5] = f2b(v1.y); o[6] = f2b(v1.z); o[7] = f2b(v1.w);
        int c = s >> 3, sub = s & 7;
        int ds = sub ^ (R & 7);
        *(uint4*)(Xg + (size_t)R * D_MODEL + c * 64 + ds * 8) = *(const uint4*)o;
        if (s == 0) {
            rowtok[R] = tok;
            roww[R] = (tok >= 0) ? tok_w[e * MAXTOK + r] : 0.0f;
        }
    }
}

// ---------------- weight transpose+convert: [e][K][N] f32 -> [e][N][K] bf16 swizzled ----------------
__global__ __launch_bounds__(256) void wconv_kernel(
    const float* __restrict__ src, ushort* __restrict__ dst, int K, int N)
{
    __shared__ float st[64][65];
    int e = blockIdx.z;
    int n0 = blockIdx.x * 64;
    int k0 = blockIdx.y * 64;
    const float* s = src + (size_t)e * K * N;
    ushort* d = dst + (size_t)e * N * K;
    for (int i = threadIdx.x; i < 4096; i += 256) {
        int kr = i >> 6, nc = i & 63;
        st[kr][nc] = s[(size_t)(k0 + kr) * N + n0 + nc];
    }
    __syncthreads();
    int c = k0 >> 6;
    #pragma unroll
    for (int it = 0; it < 2; ++it) {
        int v = threadIdx.x + it * 256;
        int nl = v >> 3, sub = v & 7;
        ushort o[8];
        #pragma unroll
        for (int j = 0; j < 8; ++j) o[j] = f2b(st[sub * 8 + j][nl]);
        int ds = sub ^ (nl & 7);
        *(uint4*)(d + (size_t)(n0 + nl) * K + c * 64 + ds * 8) = *(const uint4*)o;
    }
}

// ---------------- GEMM1: H = gelu(Xg @ W1 + b1), bf16 MFMA 128x128xK tiles ----------------
__global__ __launch_bounds__(256) void gemm1_kernel(
    const ushort* __restrict__ Xg, const ushort* __restrict__ W1T,
    const float* __restrict__ b1, const int* __restrict__ off,
    ushort* __restrict__ H)
{
    __shared__ ushort sA[128 * 64];
    __shared__ ushort sB[128 * 64];
    int e = blockIdx.y;
    int npad = off[e + 1] - off[e];
    int mt = blockIdx.x;
    if (mt * 128 >= npad) return;
    int R0 = off[e] + mt * 128;
    int nb0 = blockIdx.z * 128;
    int tid = threadIdx.x;
    int lane = tid & 63, wave = tid >> 6;
    int wr = wave >> 1, wc = wave & 1;
    int lrow = tid >> 3, lslot = tid & 7;

    const ushort* Abase = Xg + (size_t)R0 * D_MODEL;
    const ushort* Bbase = W1T + ((size_t)e * D_FF + nb0) * D_MODEL;

    f32x4 acc[4][4];
    #pragma unroll
    for (int m = 0; m < 4; ++m)
        #pragma unroll
        for (int n = 0; n < 4; ++n)
            acc[m][n] = (f32x4){0.f, 0.f, 0.f, 0.f};

    for (int kt = 0; kt < D_MODEL / 64; ++kt) {
        #pragma unroll
        for (int r = 0; r < 4; ++r) {
            int row = r * 32 + lrow;
            const ushort* ga = Abase + (size_t)row * D_MODEL + kt * 64 + lslot * 8;
            const ushort* gb = Bbase + (size_t)row * D_MODEL + kt * 64 + lslot * 8;
            __builtin_amdgcn_global_load_lds((const __attribute__((address_space(1))) void*)ga,
                (__attribute__((address_space(3))) void*)(sA + (size_t)(r * 256 + wave * 64) * 8), 16, 0, 0);
            __builtin_amdgcn_global_load_lds((const __attribute__((address_space(1))) void*)gb,
                (__attribute__((address_space(3))) void*)(sB + (size_t)(r * 256 + wave * 64) * 8), 16, 0, 0);
        }
        __syncthreads();
        #pragma unroll
        for (int ks = 0; ks < 2; ++ks) {
            short8 a[4], b[4];
            #pragma unroll
            for (int m = 0; m < 4; ++m) {
                int arow = wr * 64 + m * 16 + (lane & 15);
                int aslot = (ks * 4 + (lane >> 4)) ^ (arow & 7);
                a[m] = *(const short8*)(sA + arow * 64 + aslot * 8);
            }
            #pragma unroll
            for (int n = 0; n < 4; ++n) {
                int brow = wc * 64 + n * 16 + (lane & 15);
                int bslot = (ks * 4 + (lane >> 4)) ^ (brow & 7);
                b[n] = *(const short8*)(sB + brow * 64 + bslot * 8);
            }
            #pragma unroll
            for (int m = 0; m < 4; ++m)
                #pragma unroll
                for (int n = 0; n < 4; ++n)
                    acc[m][n] = __builtin_amdgcn_mfma_f32_16x16x32_bf16(a[m], b[n], acc[m][n], 0, 0, 0);
        }
        __syncthreads();
    }

    const float* b1e = b1 + (size_t)e * D_FF;
    #pragma unroll
    for (int m = 0; m < 4; ++m) {
        int rbase = wr * 64 + m * 16 + (lane >> 4) * 4;
        #pragma unroll
        for (int n = 0; n < 4; ++n) {
            int col = nb0 + wc * 64 + n * 16 + (lane & 15);
            float bv = b1e[col];
            int cc = col >> 6, sub = (col >> 3) & 7, el = col & 7;
            #pragma unroll
            for (int q = 0; q < 4; ++q) {
                int R = R0 + rbase + q;
                float v = acc[m][n][q] + bv;
                v = 0.5f * v * (1.0f + erff(v * 0.70710678118654752f));
                int ds = sub ^ (R & 7);
                H[(size_t)R * D_FF + cc * 64 + ds * 8 + el] = f2b(v);
            }
        }
    }
}

// ---------------- GEMM2: out[tok] += w * (H @ W2 + b2) ----------------
__global__ __launch_bounds__(256) void gemm2_kernel(
    const ushort* __restrict__ H, const ushort* __restrict__ W2T,
    const float* __restrict__ b2, const int* __restrict__ off,
    const int* __restrict__ rowtok, const float* __restrict__ roww,
    float* __restrict__ out)
{
    __shared__ ushort sA[128 * 64];
    __shared__ ushort sB[128 * 64];
    int e = blockIdx.y;
    int npad = off[e + 1] - off[e];
    int mt = blockIdx.x;
    if (mt * 128 >= npad) return;
    int R0 = off[e] + mt * 128;
    int nb0 = blockIdx.z * 128;
    int tid = threadIdx.x;
    int lane = tid & 63, wave = tid >> 6;
    int wr = wave >> 1, wc = wave & 1;
    int lrow = tid >> 3, lslot = tid & 7;

    const ushort* Abase = H + (size_t)R0 * D_FF;
    const ushort* Bbase = W2T + ((size_t)e * D_MODEL + nb0) * D_FF;

    f32x4 acc[4][4];
    #pragma unroll
    for (int m = 0; m < 4; ++m)
        #pragma unroll
        for (int n = 0; n < 4; ++n)
            acc[m][n] = (f32x4){0.f, 0.f, 0.f, 0.f};

    for (int kt = 0; kt < D_FF / 64; ++kt) {
        #pragma unroll
        for (int r = 0; r < 4; ++r) {
            int row = r * 32 + lrow;
            const ushort* ga = Abase + (size_t)row * D_FF + kt * 64 + lslot * 8;
            const ushort* gb = Bbase + (size_t)row * D_FF + kt * 64 + lslot * 8;
            __builtin_amdgcn_global_load_lds((const __attribute__((address_space(1))) void*)ga,
                (__attribute__((address_space(3))) void*)(sA + (size_t)(r * 256 + wave * 64) * 8), 16, 0, 0);
            __builtin_amdgcn_global_load_lds((const __attribute__((address_space(1))) void*)gb,
                (__attribute__((address_space(3))) void*)(sB + (size_t)(r * 256 + wave * 64) * 8), 16, 0, 0);
        }
        __syncthreads();
        #pragma unroll
        for (int ks = 0; ks < 2; ++ks) {
            short8 a[4], b[4];
            #pragma unroll
            for (int m = 0; m < 4; ++m) {
                int arow = wr * 64 + m * 16 + (lane & 15);
                int aslot = (ks * 4 + (lane >> 4)) ^ (arow & 7);
                a[m] = *(const short8*)(sA + arow * 64 + aslot * 8);
            }
            #pragma unroll
            for (int n = 0; n < 4; ++n) {
                int brow = wc * 64 + n * 16 + (lane & 15);
                int bslot = (ks * 4 + (lane >> 4)) ^ (brow & 7);
                b[n] = *(const short8*)(sB + brow * 64 + bslot * 8);
            }
            #pragma unroll
            for (int m = 0; m < 4; ++m)
                #pragma unroll
                for (int n = 0; n < 4; ++n)
                    acc[m][n] = __builtin_amdgcn_mfma_f32_16x16x32_bf16(a[m], b[n], acc[m][n], 0, 0, 0);
        }
        __syncthreads();
    }

    const float* b2e = b2 + (size_t)e * D_MODEL;
    #pragma unroll
    for (int m = 0; m < 4; ++m) {
        int rbase = wr * 64 + m * 16 + (lane >> 4) * 4;
        #pragma unroll
        for (int n = 0; n < 4; ++n) {
            int col = nb0 + wc * 64 + n * 16 + (lane & 15);
            float bv = b2e[col];
            #pragma unroll
            for (int q = 0; q < 4; ++q) {
                int R = R0 + rbase + q;
                int tok = rowtok[R];
                if (tok >= 0) {
                    float y = roww[R] * (acc[m][n][q] + bv);
                    atomicAdd(out + (size_t)tok * D_MODEL + col, y);
                }
            }
        }
    }
}

// ================= legacy fp32 fallback (known-good) =================
#define TM      32
#define FFC     128
#define KSTEP   64

__global__ __launch_bounds__(512) void ffn_kernel(
    const float* __restrict__ x,
    const float* __restrict__ W1, const float* __restrict__ b1,
    const float* __restrict__ W2, const float* __restrict__ b2,
    const int* __restrict__ cnt, const int* __restrict__ tok_ids, const float* __restrict__ tok_w,
    float* __restrict__ out)
{
    int e = blockIdx.y;
    int n = cnt[e];
    int t0 = blockIdx.x * TM;
    if (t0 >= n) return;
    int tid = threadIdx.x;

    __shared__ int   s_tok[TM];
    __shared__ float s_w[TM];
    __shared__ float s_x[TM][KSTEP];
    __shared__ float s_w1[KSTEP][FFC];
    __shared__ float s_h[TM][FFC];

    if (tid < TM) {
        int idx = t0 + tid;
        s_tok[tid] = (idx < n) ? tok_ids[e * MAXTOK + idx] : -1;
        s_w[tid]   = (idx < n) ? tok_w[e * MAXTOK + idx] : 0.0f;
    }
    __syncthreads();

    float acc[TM][2];
    #pragma unroll
    for (int i = 0; i < TM; ++i) { acc[i][0] = 0.0f; acc[i][1] = 0.0f; }

    const float* W1e = W1 + (size_t)e * D_MODEL * D_FF;
    const float* W2e = W2 + (size_t)e * D_FF * D_MODEL;
    const float* b1e = b1 + (size_t)e * D_FF;

    int ffl = (tid & 63) * 2;
    int g   = tid >> 6;

    int fb0 = blockIdx.z * (D_FF / 2);
    for (int fb = fb0; fb < fb0 + D_FF / 2; fb += FFC) {
        float bv0 = b1e[fb + ffl], bv1 = b1e[fb + ffl + 1];
        float hacc[4][2];
        #pragma unroll
        for (int j = 0; j < 4; ++j) { hacc[j][0] = bv0; hacc[j][1] = bv1; }

        for (int kb = 0; kb < D_MODEL; kb += KSTEP) {
            #pragma unroll
            for (int r = 0; r < 4; ++r) {
                int i = tid + 512 * r;
                int row = i >> 6, col = i & 63;
                int tok = s_tok[row];
                s_x[row][col] = (tok >= 0) ? x[(size_t)tok * D_MODEL + kb + col] : 0.0f;
            }
            #pragma unroll
            for (int r = 0; r < 16; ++r) {
                int i = tid + 512 * r;
                int row = i >> 7, col = i & 127;
                s_w1[row][col] = W1e[(size_t)(kb + row) * D_FF + fb + col];
            }
            __syncthreads();
            #pragma unroll 8
            for (int kk = 0; kk < KSTEP; ++kk) {
                float2 wv = *reinterpret_cast<const float2*>(&s_w1[kk][ffl]);
                #pragma unroll
                for (int j = 0; j < 4; ++j) {
                    float xv = s_x[g * 4 + j][kk];
                    hacc[j][0] += xv * wv.x;
                    hacc[j][1] += xv * wv.y;
                }
            }
            __syncthreads();
        }
        #pragma unroll
        for (int j = 0; j < 4; ++j) {
            #pragma unroll
            for (int p = 0; p < 2; ++p) {
                float v = hacc[j][p];
                v = 0.5f * v * (1.0f + erff(v * 0.70710678118654752f));
                s_h[g * 4 + j][ffl + p] = v;
            }
        }
        __syncthreads();
        for (int ff = 0; ff < FFC; ++ff) {
            const float* w2row = W2e + (size_t)(fb + ff) * D_MODEL;
            float wc0 = w2row[tid], wc1 = w2row[tid + 512];
            #pragma unroll
            for (int tt = 0; tt < TM; ++tt) {
                float hv = s_h[tt][ff];
                acc[tt][0] += hv * wc0;
                acc[tt][1] += hv * wc1;
            }
        }
        __syncthreads();
    }

    float bc0 = b2[(size_t)e * D_MODEL + tid];
    float bc1 = b2[(size_t)e * D_MODEL + tid + 512];
    if (blockIdx.z != 0) { bc0 = 0.0f; bc1 = 0.0f; }
    #pragma unroll
    for (int tt = 0; tt < TM; ++tt) {
        int tok = s_tok[tt];
        if (tok >= 0) {
            float w = s_w[tt];
            atomicAdd(&out[(size_t)tok * D_MODEL + tid],       w * (acc[tt][0] + bc0));
            atomicAdd(&out[(size_t)tok * D_MODEL + tid + 512], w * (acc[tt][1] + bc1));
        }
    }
}

extern "C" void kernel_launch(void* const* d_in, const int* in_sizes, int n_in,
                              void* d_out, int out_size, void* d_ws, size_t ws_size,
                              hipStream_t stream) {
    const float* x  = (const float*)d_in[0];
    const float* Wg = (const float*)d_in[1];
    const float* bg = (const float*)d_in[2];
    const float* W1 = (const float*)d_in[3];
    const float* b1 = (const float*)d_in[4];
    const float* W2 = (const float*)d_in[5];
    const float* b2 = (const float*)d_in[6];
    float* out = (float*)d_out;

    char* ws = (char*)d_ws;
    int*    cnt     = (int*)(ws + WS_CNT);
    int*    offp    = (int*)(ws + WS_OFFA);
    int*    tok_ids = (int*)(ws + WS_TOKIDS);
    float*  tok_w   = (float*)(ws + WS_TOKW);

    hipMemsetAsync(cnt, 0, NE * sizeof(int), stream);
    hipMemsetAsync(out, 0, (size_t)out_size * sizeof(float), stream);

    gating_kernel<<<NTOK / 256, 256, 0, stream>>>(x, Wg, bg, cnt, tok_ids, tok_w);

    if (ws_size >= WS_NEED) {
        int*    rowtok = (int*)(ws + WS_ROWTOK);
        float*  roww   = (float*)(ws + WS_ROWW);
        ushort* Xg     = (ushort*)(ws + WS_XG);
        ushort* Hb     = (ushort*)(ws + WS_H);
        ushort* W1T    = (ushort*)(ws + WS_W1T);
        ushort* W2T    = (ushort*)(ws + WS_W2T);

        scan_kernel<<<1, 64, 0, stream>>>(cnt, offp);
        wconv_kernel<<<dim3(D_FF / 64, D_MODEL / 64, NE), 256, 0, stream>>>(W1, W1T, D_MODEL, D_FF);
        wconv_kernel<<<dim3(D_MODEL / 64, D_FF / 64, NE), 256, 0, stream>>>(W2, W2T, D_FF, D_MODEL);
        gather_kernel<<<dim3(32, NE), 256, 0, stream>>>(x, cnt, offp, tok_ids, tok_w, Xg, rowtok, roww);
        gemm1_kernel<<<dim3(32, NE, D_FF / 128), 256, 0, stream>>>(Xg, W1T, b1, offp, Hb);
        gemm2_kernel<<<dim3(32, NE, D_MODEL / 128), 256, 0, stream>>>(Hb, W2T, b2, offp, rowtok, roww, out);
    } else {
        dim3 grid(MAXTOK / TM, NE, 2);
        ffn_kernel<<<grid, 512, 0, stream>>>(x, W1, b1, W2, b2, cnt, tok_ids, tok_w, out);
    }
}

// Round 3
// 570.309 us; speedup vs baseline: 9.6838x; 1.7094x over previous
//
#include <hip/hip_runtime.h>
#include <hip/hip_bf16.h>
#include <math.h>

#define D_MODEL 1024
#define D_FF    4096
#define NE      8
#define NTOK    4096   // 2*2048
#define MAXTOK  4096
#define MAXROWS 9216   // 8192 slots + 8*128 padding worst case
#define MAXMT   72     // MAXROWS/128

typedef __attribute__((ext_vector_type(8))) short short8;
typedef __attribute__((ext_vector_type(4))) float f32x4;

// ---- workspace layout (bytes) ----
#define WS_CNT     0
#define WS_OFFA    128
#define WS_TOKIDS  1024
#define WS_TOKW    (WS_TOKIDS + NE*MAXTOK*4)          // 132096
#define WS_ROWTOK  (WS_TOKW + NE*MAXTOK*4)            // 263168
#define WS_ROWW    (WS_ROWTOK + MAXROWS*4)            // 300032
#define WS_XG      524288
#define WS_H       (WS_XG + (size_t)MAXROWS*D_MODEL*2)        // +18.9MB
#define WS_W1T     (WS_H + (size_t)MAXROWS*D_FF*2)            // +75.5MB
#define WS_W2T     (WS_W1T + (size_t)NE*D_MODEL*D_FF*2)       // +67.1MB
#define WS_NEED    (WS_W2T + (size_t)NE*D_MODEL*D_FF*2)       // ~218.5MB

__device__ __forceinline__ ushort f2b(float v) {
    __hip_bfloat16 b = __float2bfloat16(v);
    return *reinterpret_cast<ushort*>(&b);
}

// fast exact-erf GELU (Abramowitz-Stegun 7.1.26, |erf err| <= 1.5e-7)
__device__ __forceinline__ float gelu_f(float v) {
    float z = fabsf(v) * 0.70710678118654752f;
    float t = 1.0f / (1.0f + 0.3275911f * z);
    float p = t * (0.254829592f + t * (-0.284496736f + t * (1.421413741f + t * (-1.453152027f + t * 1.061405429f))));
    float er = 1.0f - p * __expf(-z * z);
    float s = (v >= 0.0f) ? er : -er;
    return 0.5f * v * (1.0f + s);
}

// bijective XCD-chunked swizzle (m204): consecutive output ids land on one XCD
__device__ __forceinline__ int xcd_swz(int orig, int nwg) {
    int q = nwg >> 3, r = nwg & 7;
    int xcd = orig & 7, pos = orig >> 3;
    return (xcd < r ? xcd * (q + 1) : r * (q + 1) + (xcd - r) * q) + pos;
}

// ---------------- gating: logits -> top2 -> renorm weights -> route ----------------
__global__ __launch_bounds__(256) void gating_kernel(
    const float* __restrict__ x, const float* __restrict__ Wg, const float* __restrict__ bg,
    int* __restrict__ cnt, int* __restrict__ tok_ids, float* __restrict__ tok_w)
{
    __shared__ float s_wg[D_MODEL * NE];  // 32 KB
    int tid = threadIdx.x;
    for (int i = tid; i < D_MODEL * NE; i += 256) s_wg[i] = Wg[i];
    __syncthreads();

    int t = blockIdx.x * 256 + tid;
    float acc[NE];
    #pragma unroll
    for (int e = 0; e < NE; ++e) acc[e] = bg[e];
    const float* xr = x + (size_t)t * D_MODEL;
    for (int d = 0; d < D_MODEL; d += 4) {
        float4 xv = *reinterpret_cast<const float4*>(xr + d);
        #pragma unroll
        for (int e = 0; e < NE; ++e) {
            acc[e] += xv.x * s_wg[(d + 0) * NE + e];
            acc[e] += xv.y * s_wg[(d + 1) * NE + e];
            acc[e] += xv.z * s_wg[(d + 2) * NE + e];
            acc[e] += xv.w * s_wg[(d + 3) * NE + e];
        }
    }
    int i0 = 0;
    #pragma unroll
    for (int e = 1; e < NE; ++e) if (acc[e] > acc[i0]) i0 = e;
    int i1 = (i0 == 0) ? 1 : 0;
    #pragma unroll
    for (int e = 0; e < NE; ++e) if (e != i0 && acc[e] > acc[i1]) i1 = e;
    float e1 = __expf(acc[i1] - acc[i0]);
    float inv = 1.0f / (1.0f + e1);
    float w0 = inv, w1 = e1 * inv;

    int p0 = atomicAdd(&cnt[i0], 1);
    tok_ids[i0 * MAXTOK + p0] = t;  tok_w[i0 * MAXTOK + p0] = w0;
    int p1 = atomicAdd(&cnt[i1], 1);
    tok_ids[i1 * MAXTOK + p1] = t;  tok_w[i1 * MAXTOK + p1] = w1;
}

// ---------------- scan: 128-aligned per-expert row offsets ----------------
__global__ void scan_kernel(const int* __restrict__ cnt, int* __restrict__ off) {
    if (threadIdx.x == 0) {
        int acc = 0;
        for (int e = 0; e < NE; ++e) { off[e] = acc; acc += ((cnt[e] + 127) & ~127); }
        off[NE] = acc;
    }
}

// ---------------- gather: x rows -> compact bf16 Xg (16B-slot swizzled) ----------------
__global__ __launch_bounds__(256) void gather_kernel(
    const float* __restrict__ x, const int* __restrict__ cnt, const int* __restrict__ off,
    const int* __restrict__ tok_ids, const float* __restrict__ tok_w,
    ushort* __restrict__ Xg, int* __restrict__ rowtok, float* __restrict__ roww)
{
    int e = blockIdx.y;
    int npad = off[e + 1] - off[e];
    int r0 = blockIdx.x * 128;
    if (r0 >= npad) return;
    int n = cnt[e];
    int base = off[e];
    for (int idx = threadIdx.x; idx < 128 * 128; idx += 256) {
        int r = r0 + (idx >> 7);
        int s = idx & 127;           // 16B slot within row (8 bf16)
        int R = base + r;
        int tok = -1;
        float4 v0 = {0, 0, 0, 0}, v1 = {0, 0, 0, 0};
        if (r < n) {
            tok = tok_ids[e * MAXTOK + r];
            const float4* src = (const float4*)(x + (size_t)tok * D_MODEL + s * 8);
            v0 = src[0]; v1 = src[1];
        }
        ushort o[8];
        o[0] = f2b(v0.x); o[1] = f2b(v0.y); o[2] = f2b(v0.z); o[3] = f2b(v0.w);
        o[4] = f2b(v1.x); o[5] = f2b(v1.y); o[6] = f2b(v1.z); o[7] = f2b(v1.w);
        int c = s >> 3, sub = s & 7;
        int ds = sub ^ (R & 7);
        *(uint4*)(Xg + (size_t)R * D_MODEL + c * 64 + ds * 8) = *(const uint4*)o;
        if (s == 0) {
            rowtok[R] = tok;
            roww[R] = (tok >= 0) ? tok_w[e * MAXTOK + r] : 0.0f;
        }
    }
}

// ---------------- weight transpose+convert: [e][K][N] f32 -> [e][N][K] bf16 swizzled ----------------
__global__ __launch_bounds__(256) void wconv_kernel(
    const float* __restrict__ src, ushort* __restrict__ dst, int K, int N)
{
    __shared__ float st[64][65];
    int e = blockIdx.z;
    int n0 = blockIdx.x * 64;
    int k0 = blockIdx.y * 64;
    const float* s = src + (size_t)e * K * N;
    ushort* d = dst + (size_t)e * N * K;
    for (int i = threadIdx.x; i < 4096; i += 256) {
        int kr = i >> 6, nc = i & 63;
        st[kr][nc] = s[(size_t)(k0 + kr) * N + n0 + nc];
    }
    __syncthreads();
    int c = k0 >> 6;
    #pragma unroll
    for (int it = 0; it < 2; ++it) {
        int v = threadIdx.x + it * 256;
        int nl = v >> 3, sub = v & 7;
        ushort o[8];
        #pragma unroll
        for (int j = 0; j < 8; ++j) o[j] = f2b(st[sub * 8 + j][nl]);
        int ds = sub ^ (nl & 7);
        *(uint4*)(d + (size_t)(n0 + nl) * K + c * 64 + ds * 8) = *(const uint4*)o;
    }
}

// ---------------- GEMM1: H = gelu(Xg @ W1 + b1), dbuf+prefetch, 128x128xBK64 ----------------
__global__ __launch_bounds__(256) void gemm1_kernel(
    const ushort* __restrict__ Xg, const ushort* __restrict__ W1T,
    const float* __restrict__ b1, const int* __restrict__ off,
    ushort* __restrict__ H)
{
    __shared__ ushort sA[2][128 * 64];
    __shared__ ushort sB[2][128 * 64];
    int wid = xcd_swz(blockIdx.x, MAXMT * 32);
    int mt = wid >> 5;
    int nt = wid & 31;
    int row0 = mt << 7;
    if (row0 >= off[NE]) return;
    int e = 0;
    #pragma unroll
    for (int i = 1; i < NE; ++i) if (off[i] <= row0) e = i;
    int nb0 = nt << 7;

    int tid = threadIdx.x;
    int lane = tid & 63, wave = tid >> 6;
    int wr = wave >> 1, wc = wave & 1;
    int lrow = tid >> 3, lslot = tid & 7;

    const ushort* Abase = Xg + (size_t)row0 * D_MODEL;
    const ushort* Bbase = W1T + ((size_t)e * D_FF + nb0) * D_MODEL;

    f32x4 acc[4][4];
    #pragma unroll
    for (int m = 0; m < 4; ++m)
        #pragma unroll
        for (int n = 0; n < 4; ++n)
            acc[m][n] = (f32x4){0.f, 0.f, 0.f, 0.f};

    #define STAGE1(buf, kt) { \
        _Pragma("unroll") \
        for (int r = 0; r < 4; ++r) { \
            int row = r * 32 + lrow; \
            const ushort* ga = Abase + (size_t)row * D_MODEL + (kt) * 64 + lslot * 8; \
            const ushort* gb = Bbase + (size_t)row * D_MODEL + (kt) * 64 + lslot * 8; \
            __builtin_amdgcn_global_load_lds((const __attribute__((address_space(1))) void*)ga, \
                (__attribute__((address_space(3))) void*)(sA[buf] + (size_t)(r * 256 + wave * 64) * 8), 16, 0, 0); \
            __builtin_amdgcn_global_load_lds((const __attribute__((address_space(1))) void*)gb, \
                (__attribute__((address_space(3))) void*)(sB[buf] + (size_t)(r * 256 + wave * 64) * 8), 16, 0, 0); \
        } }

    STAGE1(0, 0);
    __syncthreads();
    for (int kt = 0; kt < D_MODEL / 64; ++kt) {
        int cur = kt & 1;
        if (kt + 1 < D_MODEL / 64) STAGE1(cur ^ 1, kt + 1);
        #pragma unroll
        for (int ks = 0; ks < 2; ++ks) {
            short8 a[4], b[4];
            #pragma unroll
            for (int m = 0; m < 4; ++m) {
                int arow = wr * 64 + m * 16 + (lane & 15);
                int aslot = (ks * 4 + (lane >> 4)) ^ (arow & 7);
                a[m] = *(const short8*)(sA[cur] + arow * 64 + aslot * 8);
            }
            #pragma unroll
            for (int n = 0; n < 4; ++n) {
                int brow = wc * 64 + n * 16 + (lane & 15);
                int bslot = (ks * 4 + (lane >> 4)) ^ (brow & 7);
                b[n] = *(const short8*)(sB[cur] + brow * 64 + bslot * 8);
            }
            #pragma unroll
            for (int m = 0; m < 4; ++m)
                #pragma unroll
                for (int n = 0; n < 4; ++n)
                    acc[m][n] = __builtin_amdgcn_mfma_f32_16x16x32_bf16(a[m], b[n], acc[m][n], 0, 0, 0);
        }
        __syncthreads();
    }

    const float* b1e = b1 + (size_t)e * D_FF;
    #pragma unroll
    for (int m = 0; m < 4; ++m) {
        int rbase = wr * 64 + m * 16 + (lane >> 4) * 4;
        #pragma unroll
        for (int n = 0; n < 4; ++n) {
            int col = nb0 + wc * 64 + n * 16 + (lane & 15);
            float bv = b1e[col];
            int cc = col >> 6, sub = (col >> 3) & 7, el = col & 7;
            #pragma unroll
            for (int q = 0; q < 4; ++q) {
                int R = row0 + rbase + q;
                float v = gelu_f(acc[m][n][q] + bv);
                int ds = sub ^ (R & 7);
                H[(size_t)R * D_FF + cc * 64 + ds * 8 + el] = f2b(v);
            }
        }
    }
}

// ---------------- GEMM2: out[tok] += w * (H @ W2 + b2), dbuf+prefetch, K-split x2 ----------------
__global__ __launch_bounds__(256) void gemm2_kernel(
    const ushort* __restrict__ H, const ushort* __restrict__ W2T,
    const float* __restrict__ b2, const int* __restrict__ off,
    const int* __restrict__ rowtok, const float* __restrict__ roww,
    float* __restrict__ out)
{
    __shared__ ushort sA[2][128 * 64];
    __shared__ ushort sB[2][128 * 64];
    int wid = xcd_swz(blockIdx.x, MAXMT * 16);
    int mt = wid >> 4;
    int ks2 = (wid >> 3) & 1;     // K-split half
    int nt = wid & 7;
    int row0 = mt << 7;
    if (row0 >= off[NE]) return;
    int e = 0;
    #pragma unroll
    for (int i = 1; i < NE; ++i) if (off[i] <= row0) e = i;
    int nb0 = nt << 7;

    int tid = threadIdx.x;
    int lane = tid & 63, wave = tid >> 6;
    int wr = wave >> 1, wc = wave & 1;
    int lrow = tid >> 3, lslot = tid & 7;

    const ushort* Abase = H + (size_t)row0 * D_FF;
    const ushort* Bbase = W2T + ((size_t)e * D_MODEL + nb0) * D_FF;

    f32x4 acc[4][4];
    #pragma unroll
    for (int m = 0; m < 4; ++m)
        #pragma unroll
        for (int n = 0; n < 4; ++n)
            acc[m][n] = (f32x4){0.f, 0.f, 0.f, 0.f};

    #define STAGE2(buf, kt) { \
        _Pragma("unroll") \
        for (int r = 0; r < 4; ++r) { \
            int row = r * 32 + lrow; \
            const ushort* ga = Abase + (size_t)row * D_FF + (kt) * 64 + lslot * 8; \
            const ushort* gb = Bbase + (size_t)row * D_FF + (kt) * 64 + lslot * 8; \
            __builtin_amdgcn_global_load_lds((const __attribute__((address_space(1))) void*)ga, \
                (__attribute__((address_space(3))) void*)(sA[buf] + (size_t)(r * 256 + wave * 64) * 8), 16, 0, 0); \
            __builtin_amdgcn_global_load_lds((const __attribute__((address_space(1))) void*)gb, \
                (__attribute__((address_space(3))) void*)(sB[buf] + (size_t)(r * 256 + wave * 64) * 8), 16, 0, 0); \
        } }

    int kt0 = ks2 * 32;
    STAGE2(0, kt0);
    __syncthreads();
    for (int i = 0; i < 32; ++i) {
        int cur = i & 1;
        if (i + 1 < 32) STAGE2(cur ^ 1, kt0 + i + 1);
        #pragma unroll
        for (int ks = 0; ks < 2; ++ks) {
            short8 a[4], b[4];
            #pragma unroll
            for (int m = 0; m < 4; ++m) {
                int arow = wr * 64 + m * 16 + (lane & 15);
                int aslot = (ks * 4 + (lane >> 4)) ^ (arow & 7);
                a[m] = *(const short8*)(sA[cur] + arow * 64 + aslot * 8);
            }
            #pragma unroll
            for (int n = 0; n < 4; ++n) {
                int brow = wc * 64 + n * 16 + (lane & 15);
                int bslot = (ks * 4 + (lane >> 4)) ^ (brow & 7);
                b[n] = *(const short8*)(sB[cur] + brow * 64 + bslot * 8);
            }
            #pragma unroll
            for (int m = 0; m < 4; ++m)
                #pragma unroll
                for (int n = 0; n < 4; ++n)
                    acc[m][n] = __builtin_amdgcn_mfma_f32_16x16x32_bf16(a[m], b[n], acc[m][n], 0, 0, 0);
        }
        __syncthreads();
    }

    const float* b2e = b2 + (size_t)e * D_MODEL;
    #pragma unroll
    for (int m = 0; m < 4; ++m) {
        int rbase = wr * 64 + m * 16 + (lane >> 4) * 4;
        #pragma unroll
        for (int n = 0; n < 4; ++n) {
            int col = nb0 + wc * 64 + n * 16 + (lane & 15);
            float bv = (ks2 == 0) ? b2e[col] : 0.0f;
            #pragma unroll
            for (int q = 0; q < 4; ++q) {
                int R = row0 + rbase + q;
                int tok = rowtok[R];
                if (tok >= 0) {
                    float y = roww[R] * (acc[m][n][q] + bv);
                    atomicAdd(out + (size_t)tok * D_MODEL + col, y);
                }
            }
        }
    }
}

// ================= legacy fp32 fallback (known-good) =================
#define TM      32
#define FFC     128
#define KSTEP   64

__global__ __launch_bounds__(512) void ffn_kernel(
    const float* __restrict__ x,
    const float* __restrict__ W1, const float* __restrict__ b1,
    const float* __restrict__ W2, const float* __restrict__ b2,
    const int* __restrict__ cnt, const int* __restrict__ tok_ids, const float* __restrict__ tok_w,
    float* __restrict__ out)
{
    int e = blockIdx.y;
    int n = cnt[e];
    int t0 = blockIdx.x * TM;
    if (t0 >= n) return;
    int tid = threadIdx.x;

    __shared__ int   s_tok[TM];
    __shared__ float s_w[TM];
    __shared__ float s_x[TM][KSTEP];
    __shared__ float s_w1[KSTEP][FFC];
    __shared__ float s_h[TM][FFC];

    if (tid < TM) {
        int idx = t0 + tid;
        s_tok[tid] = (idx < n) ? tok_ids[e * MAXTOK + idx] : -1;
        s_w[tid]   = (idx < n) ? tok_w[e * MAXTOK + idx] : 0.0f;
    }
    __syncthreads();

    float acc[TM][2];
    #pragma unroll
    for (int i = 0; i < TM; ++i) { acc[i][0] = 0.0f; acc[i][1] = 0.0f; }

    const float* W1e = W1 + (size_t)e * D_MODEL * D_FF;
    const float* W2e = W2 + (size_t)e * D_FF * D_MODEL;
    const float* b1e = b1 + (size_t)e * D_FF;

    int ffl = (tid & 63) * 2;
    int g   = tid >> 6;

    int fb0 = blockIdx.z * (D_FF / 2);
    for (int fb = fb0; fb < fb0 + D_FF / 2; fb += FFC) {
        float bv0 = b1e[fb + ffl], bv1 = b1e[fb + ffl + 1];
        float hacc[4][2];
        #pragma unroll
        for (int j = 0; j < 4; ++j) { hacc[j][0] = bv0; hacc[j][1] = bv1; }

        for (int kb = 0; kb < D_MODEL; kb += KSTEP) {
            #pragma unroll
            for (int r = 0; r < 4; ++r) {
                int i = tid + 512 * r;
                int row = i >> 6, col = i & 63;
                int tok = s_tok[row];
                s_x[row][col] = (tok >= 0) ? x[(size_t)tok * D_MODEL + kb + col] : 0.0f;
            }
            #pragma unroll
            for (int r = 0; r < 16; ++r) {
                int i = tid + 512 * r;
                int row = i >> 7, col = i & 127;
                s_w1[row][col] = W1e[(size_t)(kb + row) * D_FF + fb + col];
            }
            __syncthreads();
            #pragma unroll 8
            for (int kk = 0; kk < KSTEP; ++kk) {
                float2 wv = *reinterpret_cast<const float2*>(&s_w1[kk][ffl]);
                #pragma unroll
                for (int j = 0; j < 4; ++j) {
                    float xv = s_x[g * 4 + j][kk];
                    hacc[j][0] += xv * wv.x;
                    hacc[j][1] += xv * wv.y;
                }
            }
            __syncthreads();
        }
        #pragma unroll
        for (int j = 0; j < 4; ++j) {
            #pragma unroll
            for (int p = 0; p < 2; ++p) {
                float v = hacc[j][p];
                v = 0.5f * v * (1.0f + erff(v * 0.70710678118654752f));
                s_h[g * 4 + j][ffl + p] = v;
            }
        }
        __syncthreads();
        for (int ff = 0; ff < FFC; ++ff) {
            const float* w2row = W2e + (size_t)(fb + ff) * D_MODEL;
            float wc0 = w2row[tid], wc1 = w2row[tid + 512];
            #pragma unroll
            for (int tt = 0; tt < TM; ++tt) {
                float hv = s_h[tt][ff];
                acc[tt][0] += hv * wc0;
                acc[tt][1] += hv * wc1;
            }
        }
        __syncthreads();
    }

    float bc0 = b2[(size_t)e * D_MODEL + tid];
    float bc1 = b2[(size_t)e * D_MODEL + tid + 512];
    if (blockIdx.z != 0) { bc0 = 0.0f; bc1 = 0.0f; }
    #pragma unroll
    for (int tt = 0; tt < TM; ++tt) {
        int tok = s_tok[tt];
        if (tok >= 0) {
            float w = s_w[tt];
            atomicAdd(&out[(size_t)tok * D_MODEL + tid],       w * (acc[tt][0] + bc0));
            atomicAdd(&out[(size_t)tok * D_MODEL + tid + 512], w * (acc[tt][1] + bc1));
        }
    }
}

extern "C" void kernel_launch(void* const* d_in, const int* in_sizes, int n_in,
                              void* d_out, int out_size, void* d_ws, size_t ws_size,
                              hipStream_t stream) {
    const float* x  = (const float*)d_in[0];
    const float* Wg = (const float*)d_in[1];
    const float* bg = (const float*)d_in[2];
    const float* W1 = (const float*)d_in[3];
    const float* b1 = (const float*)d_in[4];
    const float* W2 = (const float*)d_in[5];
    const float* b2 = (const float*)d_in[6];
    float* out = (float*)d_out;

    char* ws = (char*)d_ws;
    int*    cnt     = (int*)(ws + WS_CNT);
    int*    offp    = (int*)(ws + WS_OFFA);
    int*    tok_ids = (int*)(ws + WS_TOKIDS);
    float*  tok_w   = (float*)(ws + WS_TOKW);

    hipMemsetAsync(cnt, 0, NE * sizeof(int), stream);
    hipMemsetAsync(out, 0, (size_t)out_size * sizeof(float), stream);

    gating_kernel<<<NTOK / 256, 256, 0, stream>>>(x, Wg, bg, cnt, tok_ids, tok_w);

    if (ws_size >= WS_NEED) {
        int*    rowtok = (int*)(ws + WS_ROWTOK);
        float*  roww   = (float*)(ws + WS_ROWW);
        ushort* Xg     = (ushort*)(ws + WS_XG);
        ushort* Hb     = (ushort*)(ws + WS_H);
        ushort* W1T    = (ushort*)(ws + WS_W1T);
        ushort* W2T    = (ushort*)(ws + WS_W2T);

        scan_kernel<<<1, 64, 0, stream>>>(cnt, offp);
        wconv_kernel<<<dim3(D_FF / 64, D_MODEL / 64, NE), 256, 0, stream>>>(W1, W1T, D_MODEL, D_FF);
        wconv_kernel<<<dim3(D_MODEL / 64, D_FF / 64, NE), 256, 0, stream>>>(W2, W2T, D_FF, D_MODEL);
        gather_kernel<<<dim3(32, NE), 256, 0, stream>>>(x, cnt, offp, tok_ids, tok_w, Xg, rowtok, roww);
        gemm1_kernel<<<MAXMT * 32, 256, 0, stream>>>(Xg, W1T, b1, offp, Hb);
        gemm2_kernel<<<MAXMT * 16, 256, 0, stream>>>(Hb, W2T, b2, offp, rowtok, roww, out);
    } else {
        dim3 grid(MAXTOK / TM, NE, 2);
        ffn_kernel<<<grid, 512, 0, stream>>>(x, W1, b1, W2, b2, cnt, tok_ids, tok_w, out);
    }
}

// Round 4
// 482.120 us; speedup vs baseline: 11.4552x; 1.1829x over previous
//
#include <hip/hip_runtime.h>
#include <hip/hip_bf16.h>
#include <math.h>

#define D_MODEL 1024
#define D_FF    4096
#define NE      8
#define NTOK    4096   // 2*2048
#define MAXTOK  4096

// tier-a (256-tile) geometry
#define MAXROWS 10240  // 8192 + 8*255 padding, 256-aligned
#define MAXMT   40     // MAXROWS/256
// tier-b (r3 128-tile) geometry
#define MAXROWSB 9216
#define MAXMTB   72

typedef __attribute__((ext_vector_type(8))) short short8;
typedef __attribute__((ext_vector_type(4))) float f32x4;

// ---- shared header (both tiers) ----
#define WS_CNT     0
#define WS_OFFA    128
#define WS_TOKIDS  1024
#define WS_TOKW    (WS_TOKIDS + NE*MAXTOK*4)      // 132096
#define WS_ROWTOK  (WS_TOKW + NE*MAXTOK*4)        // 263168
#define WS_ROWW    (WS_ROWTOK + MAXROWS*4)        // 304128
#define WS_TOKEXP  (WS_ROWW + MAXROWS*4)          // 345088 (+32768 < 524288)

// ---- tier-a layout: H first, then W1T+Xg (contiguous, reused as Y), then W2T ----
#define WS_H       524288
#define WS_W1T     (WS_H   + (size_t)MAXROWS*D_FF*2)        // +83.9MB
#define WS_XG      (WS_W1T + (size_t)NE*D_MODEL*D_FF*2)     // +67.1MB
#define WS_W2T     (WS_XG  + (size_t)MAXROWS*D_MODEL*2)     // +21.0MB
#define WS_NEED_A  (WS_W2T + (size_t)NE*D_MODEL*D_FF*2)     // 239,599,616

// ---- tier-b layout (exact round-3) ----
#define WSB_XG     524288
#define WSB_H      (WSB_XG  + (size_t)MAXROWSB*D_MODEL*2)
#define WSB_W1T    (WSB_H   + (size_t)MAXROWSB*D_FF*2)
#define WSB_W2T    (WSB_W1T + (size_t)NE*D_MODEL*D_FF*2)
#define WS_NEED_B  (WSB_W2T + (size_t)NE*D_MODEL*D_FF*2)    // 229,113,856 (r3-proven)

__device__ __forceinline__ ushort f2b(float v) {
    __hip_bfloat16 b = __float2bfloat16(v);
    return *reinterpret_cast<ushort*>(&b);
}

// fast exact-erf GELU (Abramowitz-Stegun 7.1.26, |erf err| <= 1.5e-7)
__device__ __forceinline__ float gelu_f(float v) {
    float z = fabsf(v) * 0.70710678118654752f;
    float t = 1.0f / (1.0f + 0.3275911f * z);
    float p = t * (0.254829592f + t * (-0.284496736f + t * (1.421413741f + t * (-1.453152027f + t * 1.061405429f))));
    float er = 1.0f - p * __expf(-z * z);
    float s = (v >= 0.0f) ? er : -er;
    return 0.5f * v * (1.0f + s);
}

// bijective XCD-chunked swizzle (m204)
__device__ __forceinline__ int xcd_swz(int orig, int nwg) {
    int q = nwg >> 3, r = nwg & 7;
    int xcd = orig & 7, pos = orig >> 3;
    return (xcd < r ? xcd * (q + 1) : r * (q + 1) + (xcd - r) * q) + pos;
}

// ---------------- gating ----------------
__global__ __launch_bounds__(256) void gating_kernel(
    const float* __restrict__ x, const float* __restrict__ Wg, const float* __restrict__ bg,
    int* __restrict__ cnt, int* __restrict__ tok_ids, float* __restrict__ tok_w,
    int* __restrict__ tokexp)
{
    __shared__ float s_wg[D_MODEL * NE];
    int tid = threadIdx.x;
    for (int i = tid; i < D_MODEL * NE; i += 256) s_wg[i] = Wg[i];
    __syncthreads();

    int t = blockIdx.x * 256 + tid;
    float acc[NE];
    #pragma unroll
    for (int e = 0; e < NE; ++e) acc[e] = bg[e];
    const float* xr = x + (size_t)t * D_MODEL;
    for (int d = 0; d < D_MODEL; d += 4) {
        float4 xv = *reinterpret_cast<const float4*>(xr + d);
        #pragma unroll
        for (int e = 0; e < NE; ++e) {
            acc[e] += xv.x * s_wg[(d + 0) * NE + e];
            acc[e] += xv.y * s_wg[(d + 1) * NE + e];
            acc[e] += xv.z * s_wg[(d + 2) * NE + e];
            acc[e] += xv.w * s_wg[(d + 3) * NE + e];
        }
    }
    int i0 = 0;
    #pragma unroll
    for (int e = 1; e < NE; ++e) if (acc[e] > acc[i0]) i0 = e;
    int i1 = (i0 == 0) ? 1 : 0;
    #pragma unroll
    for (int e = 0; e < NE; ++e) if (e != i0 && acc[e] > acc[i1]) i1 = e;
    float e1 = __expf(acc[i1] - acc[i0]);
    float inv = 1.0f / (1.0f + e1);
    float w0 = inv, w1 = e1 * inv;

    int p0 = atomicAdd(&cnt[i0], 1);
    tok_ids[i0 * MAXTOK + p0] = t;  tok_w[i0 * MAXTOK + p0] = w0;
    tokexp[t * 2 + 0] = i0 * MAXTOK + p0;
    int p1 = atomicAdd(&cnt[i1], 1);
    tok_ids[i1 * MAXTOK + p1] = t;  tok_w[i1 * MAXTOK + p1] = w1;
    tokexp[t * 2 + 1] = i1 * MAXTOK + p1;
}

// ---------------- scans ----------------
__global__ void scan256_kernel(const int* __restrict__ cnt, int* __restrict__ off) {
    if (threadIdx.x == 0) {
        int acc = 0;
        for (int e = 0; e < NE; ++e) { off[e] = acc; acc += ((cnt[e] + 255) & ~255); }
        off[NE] = acc;
    }
}
__global__ void scan128_kernel(const int* __restrict__ cnt, int* __restrict__ off) {
    if (threadIdx.x == 0) {
        int acc = 0;
        for (int e = 0; e < NE; ++e) { off[e] = acc; acc += ((cnt[e] + 127) & ~127); }
        off[NE] = acc;
    }
}

// ---------------- gather (shared; pointers select tier layout) ----------------
__global__ __launch_bounds__(256) void gather_kernel(
    const float* __restrict__ x, const int* __restrict__ cnt, const int* __restrict__ off,
    const int* __restrict__ tok_ids, const float* __restrict__ tok_w,
    ushort* __restrict__ Xg, int* __restrict__ rowtok, float* __restrict__ roww)
{
    int e = blockIdx.y;
    int npad = off[e + 1] - off[e];
    int r0 = blockIdx.x * 128;
    if (r0 >= npad) return;
    int n = cnt[e];
    int base = off[e];
    for (int idx = threadIdx.x; idx < 128 * 128; idx += 256) {
        int r = r0 + (idx >> 7);
        int s = idx & 127;
        int R = base + r;
        int tok = -1;
        float4 v0 = {0, 0, 0, 0}, v1 = {0, 0, 0, 0};
        if (r < n) {
            tok = tok_ids[e * MAXTOK + r];
            const float4* src = (const float4*)(x + (size_t)tok * D_MODEL + s * 8);
            v0 = src[0]; v1 = src[1];
        }
        ushort o[8];
        o[0] = f2b(v0.x); o[1] = f2b(v0.y); o[2] = f2b(v0.z); o[3] = f2b(v0.w);
        o[4] = f2b(v1.x); o[5] = f2b(v1.y); o[6] = f2b(v1.z); o[7] = f2b(v1.w);
        int c = s >> 3, sub = s & 7;
        int ds = sub ^ (R & 7);
        *(uint4*)(Xg + (size_t)R * D_MODEL + c * 64 + ds * 8) = *(const uint4*)o;
        if (s == 0) {
            rowtok[R] = tok;
            roww[R] = (tok >= 0) ? tok_w[e * MAXTOK + r] : 0.0f;
        }
    }
}

// ---------------- weight transpose+convert ----------------
__global__ __launch_bounds__(256) void wconv_kernel(
    const float* __restrict__ src, ushort* __restrict__ dst, int K, int N)
{
    __shared__ float st[64][65];
    int e = blockIdx.z;
    int n0 = blockIdx.x * 64;
    int k0 = blockIdx.y * 64;
    const float* s = src + (size_t)e * K * N;
    ushort* d = dst + (size_t)e * N * K;
    for (int i = threadIdx.x; i < 4096; i += 256) {
        int kr = i >> 6, nc = i & 63;
        st[kr][nc] = s[(size_t)(k0 + kr) * N + n0 + nc];
    }
    __syncthreads();
    int c = k0 >> 6;
    #pragma unroll
    for (int it = 0; it < 2; ++it) {
        int v = threadIdx.x + it * 256;
        int nl = v >> 3, sub = v & 7;
        ushort o[8];
        #pragma unroll
        for (int j = 0; j < 8; ++j) o[j] = f2b(st[sub * 8 + j][nl]);
        int ds = sub ^ (nl & 7);
        *(uint4*)(d + (size_t)(n0 + nl) * K + c * 64 + ds * 8) = *(const uint4*)o;
    }
}

// ================= tier-a: 256x256 GEMMs =================

// GEMM1: H = gelu(Xg @ W1 + b1). 512 thr, 8 waves (2Mx4N), BK=64, dbuf.
__global__ __launch_bounds__(512, 2) void gemm1_256(
    const ushort* __restrict__ Xg, const ushort* __restrict__ W1T,
    const float* __restrict__ b1, const int* __restrict__ off,
    ushort* __restrict__ H)
{
    __shared__ ushort smem[65536];  // 128 KB: A dbuf [0,32K), B dbuf [32K,64K) ushorts
    int wid = xcd_swz(blockIdx.x, MAXMT * 16);
    int mt = wid >> 4, nt = wid & 15;
    int row0 = mt << 8;
    if (row0 >= off[NE]) return;
    int e = 0;
    #pragma unroll
    for (int i = 1; i < NE; ++i) if (off[i] <= row0) e = i;
    int nb0 = nt << 8;
    int tid = threadIdx.x;
    int lane = tid & 63, wave = tid >> 6;
    int wr = wave >> 2, wc = wave & 3;

    const ushort* Abase = Xg + (size_t)row0 * D_MODEL;
    const ushort* Bbase = W1T + ((size_t)e * D_FF + nb0) * D_MODEL;

    f32x4 acc[8][4];
    #pragma unroll
    for (int m = 0; m < 8; ++m)
        #pragma unroll
        for (int n = 0; n < 4; ++n)
            acc[m][n] = (f32x4){0.f, 0.f, 0.f, 0.f};

    #define STAGE1(buf, kt) { \
        _Pragma("unroll") \
        for (int r = 0; r < 4; ++r) { \
            int flat = r * 512 + tid; int row_ = flat >> 3, sl = flat & 7; \
            __builtin_amdgcn_global_load_lds((const __attribute__((address_space(1))) void*)(Abase + (size_t)row_ * D_MODEL + (kt) * 64 + sl * 8), \
                (__attribute__((address_space(3))) void*)(smem + (buf) * 16384 + flat * 8), 16, 0, 0); \
            __builtin_amdgcn_global_load_lds((const __attribute__((address_space(1))) void*)(Bbase + (size_t)row_ * D_MODEL + (kt) * 64 + sl * 8), \
                (__attribute__((address_space(3))) void*)(smem + 32768 + (buf) * 16384 + flat * 8), 16, 0, 0); \
        } }

    STAGE1(0, 0);
    __syncthreads();
    for (int kt = 0; kt < 16; ++kt) {
        int cur = kt & 1;
        if (kt + 1 < 16) STAGE1(cur ^ 1, kt + 1);
        const ushort* sAc = smem + cur * 16384;
        const ushort* sBc = smem + 32768 + cur * 16384;
        #pragma unroll
        for (int ks = 0; ks < 2; ++ks) {
            int j = ks * 4 + (lane >> 4);
            short8 b[4];
            #pragma unroll
            for (int n = 0; n < 4; ++n) {
                int brow = wc * 64 + n * 16 + (lane & 15);
                b[n] = *(const short8*)(sBc + brow * 64 + (j ^ (brow & 7)) * 8);
            }
            #pragma unroll
            for (int m = 0; m < 8; ++m) {
                int arow = wr * 128 + m * 16 + (lane & 15);
                short8 a = *(const short8*)(sAc + arow * 64 + (j ^ (arow & 7)) * 8);
                #pragma unroll
                for (int n = 0; n < 4; ++n)
                    acc[m][n] = __builtin_amdgcn_mfma_f32_16x16x32_bf16(a, b[n], acc[m][n], 0, 0, 0);
            }
        }
        __syncthreads();
    }

    // epilogue: gelu -> LDS (global-swizzled layout) -> coalesced 16B stores
    const float* b1e = b1 + (size_t)e * D_FF + nb0;
    #pragma unroll
    for (int n = 0; n < 4; ++n) {
        int col = wc * 64 + n * 16 + (lane & 15);
        float bv = b1e[col];
        int gl = col >> 3, el = col & 7;
        #pragma unroll
        for (int m = 0; m < 8; ++m) {
            int rbase = wr * 128 + m * 16 + (lane >> 4) * 4;
            #pragma unroll
            for (int q = 0; q < 4; ++q) {
                int row = rbase + q;
                float v = gelu_f(acc[m][n][q] + bv);
                int g = (gl & ~7) | ((gl ^ row) & 7);
                smem[row * 256 + g * 8 + el] = f2b(v);
            }
        }
    }
    __syncthreads();
    #pragma unroll
    for (int it = 0; it < 16; ++it) {
        int flat = it * 512 + tid;
        int row = flat >> 5, g = flat & 31;
        *(uint4*)(H + (size_t)(row0 + row) * D_FF + nb0 + g * 8) = *(const uint4*)(smem + flat * 8);
    }
}

// GEMM2: Y[ks] = H @ W2 (K-split) + (ks==0 ? b2 : 0). Plain f32 stores, no atomics.
__global__ __launch_bounds__(512, 2) void gemm2_256(
    const ushort* __restrict__ H, const ushort* __restrict__ W2T,
    const float* __restrict__ b2, const int* __restrict__ off,
    float* __restrict__ Y, int nks)
{
    __shared__ ushort smem[65536];
    int per = 4 * nks;
    int wid = xcd_swz(blockIdx.x, MAXMT * per);
    int mt = wid / per;
    int rrem = wid - mt * per;
    int nt = rrem & 3, ks = rrem >> 2;
    int row0 = mt << 8;
    if (row0 >= off[NE]) return;
    int e = 0;
    #pragma unroll
    for (int i = 1; i < NE; ++i) if (off[i] <= row0) e = i;
    int nb0 = nt << 8;
    int tid = threadIdx.x;
    int lane = tid & 63, wave = tid >> 6;
    int wr = wave >> 2, wc = wave & 3;
    int KTS = 64 / nks;
    int kt0 = ks * KTS;

    const ushort* Abase = H + (size_t)row0 * D_FF;
    const ushort* Bbase = W2T + ((size_t)e * D_MODEL + nb0) * D_FF;

    f32x4 acc[8][4];
    #pragma unroll
    for (int m = 0; m < 8; ++m)
        #pragma unroll
        for (int n = 0; n < 4; ++n)
            acc[m][n] = (f32x4){0.f, 0.f, 0.f, 0.f};

    #define STAGE2(buf, kt) { \
        _Pragma("unroll") \
        for (int r = 0; r < 4; ++r) { \
            int flat = r * 512 + tid; int row_ = flat >> 3, sl = flat & 7; \
            __builtin_amdgcn_global_load_lds((const __attribute__((address_space(1))) void*)(Abase + (size_t)row_ * D_FF + (kt) * 64 + sl * 8), \
                (__attribute__((address_space(3))) void*)(smem + (buf) * 16384 + flat * 8), 16, 0, 0); \
            __builtin_amdgcn_global_load_lds((const __attribute__((address_space(1))) void*)(Bbase + (size_t)row_ * D_FF + (kt) * 64 + sl * 8), \
                (__attribute__((address_space(3))) void*)(smem + 32768 + (buf) * 16384 + flat * 8), 16, 0, 0); \
        } }

    STAGE2(0, kt0);
    __syncthreads();
    for (int i = 0; i < KTS; ++i) {
        int cur = i & 1;
        if (i + 1 < KTS) STAGE2(cur ^ 1, kt0 + i + 1);
        const ushort* sAc = smem + cur * 16384;
        const ushort* sBc = smem + 32768 + cur * 16384;
        #pragma unroll
        for (int ksu = 0; ksu < 2; ++ksu) {
            int j = ksu * 4 + (lane >> 4);
            short8 b[4];
            #pragma unroll
            for (int n = 0; n < 4; ++n) {
                int brow = wc * 64 + n * 16 + (lane & 15);
                b[n] = *(const short8*)(sBc + brow * 64 + (j ^ (brow & 7)) * 8);
            }
            #pragma unroll
            for (int m = 0; m < 8; ++m) {
                int arow = wr * 128 + m * 16 + (lane & 15);
                short8 a = *(const short8*)(sAc + arow * 64 + (j ^ (arow & 7)) * 8);
                #pragma unroll
                for (int n = 0; n < 4; ++n)
                    acc[m][n] = __builtin_amdgcn_mfma_f32_16x16x32_bf16(a, b[n], acc[m][n], 0, 0, 0);
            }
        }
        __syncthreads();
    }

    float* Yb = Y + (size_t)ks * MAXROWS * D_MODEL;
    const float* b2e = b2 + (size_t)e * D_MODEL + nb0;
    #pragma unroll
    for (int n = 0; n < 4; ++n) {
        int col = wc * 64 + n * 16 + (lane & 15);
        float bv = (ks == 0) ? b2e[col] : 0.0f;
        #pragma unroll
        for (int m = 0; m < 8; ++m) {
            int rbase = wr * 128 + m * 16 + (lane >> 4) * 4;
            #pragma unroll
            for (int q = 0; q < 4; ++q)
                Yb[(size_t)(row0 + rbase + q) * D_MODEL + nb0 + col] = acc[m][n][q] + bv;
        }
    }
}

// combine: out[t] = sum_k w_k * sum_s Y_s[R_k]
__global__ __launch_bounds__(256) void combine_kernel(
    const float* __restrict__ Y, const int* __restrict__ off,
    const int* __restrict__ tokexp, const float* __restrict__ tok_w,
    float* __restrict__ out, int nks)
{
    int t = blockIdx.x;
    int pos0 = tokexp[2 * t], pos1 = tokexp[2 * t + 1];
    int e0 = pos0 >> 12, p0 = pos0 & (MAXTOK - 1);
    int e1 = pos1 >> 12, p1 = pos1 & (MAXTOK - 1);
    size_t R0 = off[e0] + p0, R1 = off[e1] + p1;
    float w0 = tok_w[pos0], w1 = tok_w[pos1];
    int c = threadIdx.x * 4;
    float y0x = 0, y0y = 0, y0z = 0, y0w = 0;
    float y1x = 0, y1y = 0, y1z = 0, y1w = 0;
    for (int s = 0; s < nks; ++s) {
        const float* Ys = Y + (size_t)s * MAXROWS * D_MODEL;
        float4 a = *(const float4*)(Ys + R0 * D_MODEL + c);
        float4 b = *(const float4*)(Ys + R1 * D_MODEL + c);
        y0x += a.x; y0y += a.y; y0z += a.z; y0w += a.w;
        y1x += b.x; y1y += b.y; y1z += b.z; y1w += b.w;
    }
    float4 o;
    o.x = w0 * y0x + w1 * y1x;
    o.y = w0 * y0y + w1 * y1y;
    o.z = w0 * y0z + w1 * y1z;
    o.w = w0 * y0w + w1 * y1w;
    *(float4*)(out + (size_t)t * D_MODEL + c) = o;
}

// ================= tier-b: exact round-3 128x128 GEMMs =================
__global__ __launch_bounds__(256) void gemm1_128(
    const ushort* __restrict__ Xg, const ushort* __restrict__ W1T,
    const float* __restrict__ b1, const int* __restrict__ off,
    ushort* __restrict__ H)
{
    __shared__ ushort sA[2][128 * 64];
    __shared__ ushort sB[2][128 * 64];
    int wid = xcd_swz(blockIdx.x, MAXMTB * 32);
    int mt = wid >> 5;
    int nt = wid & 31;
    int row0 = mt << 7;
    if (row0 >= off[NE]) return;
    int e = 0;
    #pragma unroll
    for (int i = 1; i < NE; ++i) if (off[i] <= row0) e = i;
    int nb0 = nt << 7;
    int tid = threadIdx.x;
    int lane = tid & 63, wave = tid >> 6;
    int wr = wave >> 1, wc = wave & 1;
    int lrow = tid >> 3, lslot = tid & 7;

    const ushort* Abase = Xg + (size_t)row0 * D_MODEL;
    const ushort* Bbase = W1T + ((size_t)e * D_FF + nb0) * D_MODEL;

    f32x4 acc[4][4];
    #pragma unroll
    for (int m = 0; m < 4; ++m)
        #pragma unroll
        for (int n = 0; n < 4; ++n)
            acc[m][n] = (f32x4){0.f, 0.f, 0.f, 0.f};

    #define STAGE1B(buf, kt) { \
        _Pragma("unroll") \
        for (int r = 0; r < 4; ++r) { \
            int row = r * 32 + lrow; \
            const ushort* ga = Abase + (size_t)row * D_MODEL + (kt) * 64 + lslot * 8; \
            const ushort* gb = Bbase + (size_t)row * D_MODEL + (kt) * 64 + lslot * 8; \
            __builtin_amdgcn_global_load_lds((const __attribute__((address_space(1))) void*)ga, \
                (__attribute__((address_space(3))) void*)(sA[buf] + (size_t)(r * 256 + wave * 64) * 8), 16, 0, 0); \
            __builtin_amdgcn_global_load_lds((const __attribute__((address_space(1))) void*)gb, \
                (__attribute__((address_space(3))) void*)(sB[buf] + (size_t)(r * 256 + wave * 64) * 8), 16, 0, 0); \
        } }

    STAGE1B(0, 0);
    __syncthreads();
    for (int kt = 0; kt < D_MODEL / 64; ++kt) {
        int cur = kt & 1;
        if (kt + 1 < D_MODEL / 64) STAGE1B(cur ^ 1, kt + 1);
        #pragma unroll
        for (int ks = 0; ks < 2; ++ks) {
            short8 a[4], b[4];
            #pragma unroll
            for (int m = 0; m < 4; ++m) {
                int arow = wr * 64 + m * 16 + (lane & 15);
                int aslot = (ks * 4 + (lane >> 4)) ^ (arow & 7);
                a[m] = *(const short8*)(sA[cur] + arow * 64 + aslot * 8);
            }
            #pragma unroll
            for (int n = 0; n < 4; ++n) {
                int brow = wc * 64 + n * 16 + (lane & 15);
                int bslot = (ks * 4 + (lane >> 4)) ^ (brow & 7);
                b[n] = *(const short8*)(sB[cur] + brow * 64 + bslot * 8);
            }
            #pragma unroll
            for (int m = 0; m < 4; ++m)
                #pragma unroll
                for (int n = 0; n < 4; ++n)
                    acc[m][n] = __builtin_amdgcn_mfma_f32_16x16x32_bf16(a[m], b[n], acc[m][n], 0, 0, 0);
        }
        __syncthreads();
    }

    const float* b1e = b1 + (size_t)e * D_FF;
    #pragma unroll
    for (int m = 0; m < 4; ++m) {
        int rbase = wr * 64 + m * 16 + (lane >> 4) * 4;
        #pragma unroll
        for (int n = 0; n < 4; ++n) {
            int col = nb0 + wc * 64 + n * 16 + (lane & 15);
            float bv = b1e[col];
            int cc = col >> 6, sub = (col >> 3) & 7, el = col & 7;
            #pragma unroll
            for (int q = 0; q < 4; ++q) {
                int R = row0 + rbase + q;
                float v = gelu_f(acc[m][n][q] + bv);
                int ds = sub ^ (R & 7);
                H[(size_t)R * D_FF + cc * 64 + ds * 8 + el] = f2b(v);
            }
        }
    }
}

__global__ __launch_bounds__(256) void gemm2_128(
    const ushort* __restrict__ H, const ushort* __restrict__ W2T,
    const float* __restrict__ b2, const int* __restrict__ off,
    const int* __restrict__ rowtok, const float* __restrict__ roww,
    float* __restrict__ out)
{
    __shared__ ushort sA[2][128 * 64];
    __shared__ ushort sB[2][128 * 64];
    int wid = xcd_swz(blockIdx.x, MAXMTB * 16);
    int mt = wid >> 4;
    int ks2 = (wid >> 3) & 1;
    int nt = wid & 7;
    int row0 = mt << 7;
    if (row0 >= off[NE]) return;
    int e = 0;
    #pragma unroll
    for (int i = 1; i < NE; ++i) if (off[i] <= row0) e = i;
    int nb0 = nt << 7;
    int tid = threadIdx.x;
    int lane = tid & 63, wave = tid >> 6;
    int wr = wave >> 1, wc = wave & 1;
    int lrow = tid >> 3, lslot = tid & 7;

    const ushort* Abase = H + (size_t)row0 * D_FF;
    const ushort* Bbase = W2T + ((size_t)e * D_MODEL + nb0) * D_FF;

    f32x4 acc[4][4];
    #pragma unroll
    for (int m = 0; m < 4; ++m)
        #pragma unroll
        for (int n = 0; n < 4; ++n)
            acc[m][n] = (f32x4){0.f, 0.f, 0.f, 0.f};

    #define STAGE2B(buf, kt) { \
        _Pragma("unroll") \
        for (int r = 0; r < 4; ++r) { \
            int row = r * 32 + lrow; \
            const ushort* ga = Abase + (size_t)row * D_FF + (kt) * 64 + lslot * 8; \
            const ushort* gb = Bbase + (size_t)row * D_FF + (kt) * 64 + lslot * 8; \
            __builtin_amdgcn_global_load_lds((const __attribute__((address_space(1))) void*)ga, \
                (__attribute__((address_space(3))) void*)(sA[buf] + (size_t)(r * 256 + wave * 64) * 8), 16, 0, 0); \
            __builtin_amdgcn_global_load_lds((const __attribute__((address_space(1))) void*)gb, \
                (__attribute__((address_space(3))) void*)(sB[buf] + (size_t)(r * 256 + wave * 64) * 8), 16, 0, 0); \
        } }

    int kt0 = ks2 * 32;
    STAGE2B(0, kt0);
    __syncthreads();
    for (int i = 0; i < 32; ++i) {
        int cur = i & 1;
        if (i + 1 < 32) STAGE2B(cur ^ 1, kt0 + i + 1);
        #pragma unroll
        for (int ks = 0; ks < 2; ++ks) {
            short8 a[4], b[4];
            #pragma unroll
            for (int m = 0; m < 4; ++m) {
                int arow = wr * 64 + m * 16 + (lane & 15);
                int aslot = (ks * 4 + (lane >> 4)) ^ (arow & 7);
                a[m] = *(const short8*)(sA[cur] + arow * 64 + aslot * 8);
            }
            #pragma unroll
            for (int n = 0; n < 4; ++n) {
                int brow = wc * 64 + n * 16 + (lane & 15);
                int bslot = (ks * 4 + (lane >> 4)) ^ (brow & 7);
                b[n] = *(const short8*)(sB[cur] + brow * 64 + bslot * 8);
            }
            #pragma unroll
            for (int m = 0; m < 4; ++m)
                #pragma unroll
                for (int n = 0; n < 4; ++n)
                    acc[m][n] = __builtin_amdgcn_mfma_f32_16x16x32_bf16(a[m], b[n], acc[m][n], 0, 0, 0);
        }
        __syncthreads();
    }

    const float* b2e = b2 + (size_t)e * D_MODEL;
    #pragma unroll
    for (int m = 0; m < 4; ++m) {
        int rbase = wr * 64 + m * 16 + (lane >> 4) * 4;
        #pragma unroll
        for (int n = 0; n < 4; ++n) {
            int col = nb0 + wc * 64 + n * 16 + (lane & 15);
            float bv = (ks2 == 0) ? b2e[col] : 0.0f;
            #pragma unroll
            for (int q = 0; q < 4; ++q) {
                int R = row0 + rbase + q;
                int tok = rowtok[R];
                if (tok >= 0) {
                    float y = roww[R] * (acc[m][n][q] + bv);
                    atomicAdd(out + (size_t)tok * D_MODEL + col, y);
                }
            }
        }
    }
}

// ================= legacy fp32 fallback =================
#define TM      32
#define FFC     128
#define KSTEP   64

__global__ __launch_bounds__(512) void ffn_kernel(
    const float* __restrict__ x,
    const float* __restrict__ W1, const float* __restrict__ b1,
    const float* __restrict__ W2, const float* __restrict__ b2,
    const int* __restrict__ cnt, const int* __restrict__ tok_ids, const float* __restrict__ tok_w,
    float* __restrict__ out)
{
    int e = blockIdx.y;
    int n = cnt[e];
    int t0 = blockIdx.x * TM;
    if (t0 >= n) return;
    int tid = threadIdx.x;

    __shared__ int   s_tok[TM];
    __shared__ float s_w[TM];
    __shared__ float s_x[TM][KSTEP];
    __shared__ float s_w1[KSTEP][FFC];
    __shared__ float s_h[TM][FFC];

    if (tid < TM) {
        int idx = t0 + tid;
        s_tok[tid] = (idx < n) ? tok_ids[e * MAXTOK + idx] : -1;
        s_w[tid]   = (idx < n) ? tok_w[e * MAXTOK + idx] : 0.0f;
    }
    __syncthreads();

    float acc[TM][2];
    #pragma unroll
    for (int i = 0; i < TM; ++i) { acc[i][0] = 0.0f; acc[i][1] = 0.0f; }

    const float* W1e = W1 + (size_t)e * D_MODEL * D_FF;
    const float* W2e = W2 + (size_t)e * D_FF * D_MODEL;
    const float* b1e = b1 + (size_t)e * D_FF;

    int ffl = (tid & 63) * 2;
    int g   = tid >> 6;

    int fb0 = blockIdx.z * (D_FF / 2);
    for (int fb = fb0; fb < fb0 + D_FF / 2; fb += FFC) {
        float bv0 = b1e[fb + ffl], bv1 = b1e[fb + ffl + 1];
        float hacc[4][2];
        #pragma unroll
        for (int j = 0; j < 4; ++j) { hacc[j][0] = bv0; hacc[j][1] = bv1; }

        for (int kb = 0; kb < D_MODEL; kb += KSTEP) {
            #pragma unroll
            for (int r = 0; r < 4; ++r) {
                int i = tid + 512 * r;
                int row = i >> 6, col = i & 63;
                int tok = s_tok[row];
                s_x[row][col] = (tok >= 0) ? x[(size_t)tok * D_MODEL + kb + col] : 0.0f;
            }
            #pragma unroll
            for (int r = 0; r < 16; ++r) {
                int i = tid + 512 * r;
                int row = i >> 7, col = i & 127;
                s_w1[row][col] = W1e[(size_t)(kb + row) * D_FF + fb + col];
            }
            __syncthreads();
            #pragma unroll 8
            for (int kk = 0; kk < KSTEP; ++kk) {
                float2 wv = *reinterpret_cast<const float2*>(&s_w1[kk][ffl]);
                #pragma unroll
                for (int j = 0; j < 4; ++j) {
                    float xv = s_x[g * 4 + j][kk];
                    hacc[j][0] += xv * wv.x;
                    hacc[j][1] += xv * wv.y;
                }
            }
            __syncthreads();
        }
        #pragma unroll
        for (int j = 0; j < 4; ++j) {
            #pragma unroll
            for (int p = 0; p < 2; ++p) {
                float v = hacc[j][p];
                v = 0.5f * v * (1.0f + erff(v * 0.70710678118654752f));
                s_h[g * 4 + j][ffl + p] = v;
            }
        }
        __syncthreads();
        for (int ff = 0; ff < FFC; ++ff) {
            const float* w2row = W2e + (size_t)(fb + ff) * D_MODEL;
            float wc0 = w2row[tid], wc1 = w2row[tid + 512];
            #pragma unroll
            for (int tt = 0; tt < TM; ++tt) {
                float hv = s_h[tt][ff];
                acc[tt][0] += hv * wc0;
                acc[tt][1] += hv * wc1;
            }
        }
        __syncthreads();
    }

    float bc0 = b2[(size_t)e * D_MODEL + tid];
    float bc1 = b2[(size_t)e * D_MODEL + tid + 512];
    if (blockIdx.z != 0) { bc0 = 0.0f; bc1 = 0.0f; }
    #pragma unroll
    for (int tt = 0; tt < TM; ++tt) {
        int tok = s_tok[tt];
        if (tok >= 0) {
            float w = s_w[tt];
            atomicAdd(&out[(size_t)tok * D_MODEL + tid],       w * (acc[tt][0] + bc0));
            atomicAdd(&out[(size_t)tok * D_MODEL + tid + 512], w * (acc[tt][1] + bc1));
        }
    }
}

extern "C" void kernel_launch(void* const* d_in, const int* in_sizes, int n_in,
                              void* d_out, int out_size, void* d_ws, size_t ws_size,
                              hipStream_t stream) {
    const float* x  = (const float*)d_in[0];
    const float* Wg = (const float*)d_in[1];
    const float* bg = (const float*)d_in[2];
    const float* W1 = (const float*)d_in[3];
    const float* b1 = (const float*)d_in[4];
    const float* W2 = (const float*)d_in[5];
    const float* b2 = (const float*)d_in[6];
    float* out = (float*)d_out;

    char* ws = (char*)d_ws;
    int*    cnt     = (int*)(ws + WS_CNT);
    int*    offp    = (int*)(ws + WS_OFFA);
    int*    tok_ids = (int*)(ws + WS_TOKIDS);
    float*  tok_w   = (float*)(ws + WS_TOKW);
    int*    rowtok  = (int*)(ws + WS_ROWTOK);
    float*  roww    = (float*)(ws + WS_ROWW);
    int*    tokexp  = (int*)(ws + WS_TOKEXP);

    hipMemsetAsync(cnt, 0, NE * sizeof(int), stream);
    gating_kernel<<<NTOK / 256, 256, 0, stream>>>(x, Wg, bg, cnt, tok_ids, tok_w, tokexp);

    if (ws_size >= WS_NEED_A) {
        ushort* Hb  = (ushort*)(ws + WS_H);
        ushort* W1T = (ushort*)(ws + WS_W1T);
        ushort* Xg  = (ushort*)(ws + WS_XG);
        ushort* W2T = (ushort*)(ws + WS_W2T);
        float*  Y   = (float*)(ws + WS_W1T);   // aliases dead W1T+Xg after gemm1
        const int nks = 2;

        scan256_kernel<<<1, 64, 0, stream>>>(cnt, offp);
        wconv_kernel<<<dim3(D_FF / 64, D_MODEL / 64, NE), 256, 0, stream>>>(W1, W1T, D_MODEL, D_FF);
        wconv_kernel<<<dim3(D_MODEL / 64, D_FF / 64, NE), 256, 0, stream>>>(W2, W2T, D_FF, D_MODEL);
        gather_kernel<<<dim3(32, NE), 256, 0, stream>>>(x, cnt, offp, tok_ids, tok_w, Xg, rowtok, roww);
        gemm1_256<<<MAXMT * 16, 512, 0, stream>>>(Xg, W1T, b1, offp, Hb);
        gemm2_256<<<MAXMT * 4 * nks, 512, 0, stream>>>(Hb, W2T, b2, offp, Y, nks);
        combine_kernel<<<NTOK, 256, 0, stream>>>(Y, offp, tokexp, tok_w, out, nks);
    } else if (ws_size >= WS_NEED_B) {
        ushort* Xg  = (ushort*)(ws + WSB_XG);
        ushort* Hb  = (ushort*)(ws + WSB_H);
        ushort* W1T = (ushort*)(ws + WSB_W1T);
        ushort* W2T = (ushort*)(ws + WSB_W2T);

        hipMemsetAsync(out, 0, (size_t)out_size * sizeof(float), stream);
        scan128_kernel<<<1, 64, 0, stream>>>(cnt, offp);
        wconv_kernel<<<dim3(D_FF / 64, D_MODEL / 64, NE), 256, 0, stream>>>(W1, W1T, D_MODEL, D_FF);
        wconv_kernel<<<dim3(D_MODEL / 64, D_FF / 64, NE), 256, 0, stream>>>(W2, W2T, D_FF, D_MODEL);
        gather_kernel<<<dim3(32, NE), 256, 0, stream>>>(x, cnt, offp, tok_ids, tok_w, Xg, rowtok, roww);
        gemm1_128<<<MAXMTB * 32, 256, 0, stream>>>(Xg, W1T, b1, offp, Hb);
        gemm2_128<<<MAXMTB * 16, 256, 0, stream>>>(Hb, W2T, b2, offp, rowtok, roww, out);
    } else {
        hipMemsetAsync(out, 0, (size_t)out_size * sizeof(float), stream);
        dim3 grid(MAXTOK / TM, NE, 2);
        ffn_kernel<<<grid, 512, 0, stream>>>(x, W1, b1, W2, b2, cnt, tok_ids, tok_w, out);
    }
}

// Round 5
// 479.036 us; speedup vs baseline: 11.5289x; 1.0064x over previous
//
#include <hip/hip_runtime.h>
#include <hip/hip_bf16.h>
#include <math.h>

#define D_MODEL 1024
#define D_FF    4096
#define NE      8
#define NTOK    4096   // 2*2048
#define MAXTOK  4096

#define MAXROWS 10240  // 8192 + 8*255 padding, 256-aligned
#define MAXMT   40     // MAXROWS/256

typedef __attribute__((ext_vector_type(8))) short short8;
typedef __attribute__((ext_vector_type(4))) float f32x4;

// ---- workspace layout ----
#define WS_CNT     0
#define WS_OFFA    128
#define WS_TOKIDS  1024
#define WS_TOKW    (WS_TOKIDS + NE*MAXTOK*4)      // 132096
#define WS_ROWTOK  (WS_TOKW + NE*MAXTOK*4)        // 263168
#define WS_ROWW    (WS_ROWTOK + MAXROWS*4)        // 304128
#define WS_TOKEXP  (WS_ROWW + MAXROWS*4)          // 345088

#define WS_H       524288
#define WS_W1T     (WS_H   + (size_t)MAXROWS*D_FF*2)        // +83.9MB
#define WS_XG      (WS_W1T + (size_t)NE*D_MODEL*D_FF*2)     // +67.1MB
#define WS_W2T     (WS_XG  + (size_t)MAXROWS*D_MODEL*2)     // +21.0MB
#define WS_NEED_A  (WS_W2T + (size_t)NE*D_MODEL*D_FF*2)     // 239,599,616

__device__ __forceinline__ ushort f2b(float v) {
    __hip_bfloat16 b = __float2bfloat16(v);
    return *reinterpret_cast<ushort*>(&b);
}

// fast exact-erf GELU (Abramowitz-Stegun 7.1.26, |erf err| <= 1.5e-7)
__device__ __forceinline__ float gelu_f(float v) {
    float z = fabsf(v) * 0.70710678118654752f;
    float t = 1.0f / (1.0f + 0.3275911f * z);
    float p = t * (0.254829592f + t * (-0.284496736f + t * (1.421413741f + t * (-1.453152027f + t * 1.061405429f))));
    float er = 1.0f - p * __expf(-z * z);
    float s = (v >= 0.0f) ? er : -er;
    return 0.5f * v * (1.0f + s);
}

// bijective XCD-chunked swizzle (m204)
__device__ __forceinline__ int xcd_swz(int orig, int nwg) {
    int q = nwg >> 3, r = nwg & 7;
    int xcd = orig & 7, pos = orig >> 3;
    return (xcd < r ? xcd * (q + 1) : r * (q + 1) + (xcd - r) * q) + pos;
}

// global pre-swizzle position for 8-elem slot `sub` (0..7) of a 64-col k-group, row R:
// kh = sub>>2 (k-half), jj = sub&3; stored at kh*32 + ((jj + ((R>>1)&3))&3)*8
__device__ __forceinline__ int swz_pos(int sub, int row) {
    int kh = sub >> 2, jj = sub & 3;
    int q = (jj + ((row >> 1) & 3)) & 3;
    return kh * 32 + q * 8;
}

// ---------------- gating ----------------
__global__ __launch_bounds__(256) void gating_kernel(
    const float* __restrict__ x, const float* __restrict__ Wg, const float* __restrict__ bg,
    int* __restrict__ cnt, int* __restrict__ tok_ids, float* __restrict__ tok_w,
    int* __restrict__ tokexp)
{
    __shared__ float s_wg[D_MODEL * NE];
    int tid = threadIdx.x;
    for (int i = tid; i < D_MODEL * NE; i += 256) s_wg[i] = Wg[i];
    __syncthreads();

    int t = blockIdx.x * 256 + tid;
    float acc[NE];
    #pragma unroll
    for (int e = 0; e < NE; ++e) acc[e] = bg[e];
    const float* xr = x + (size_t)t * D_MODEL;
    for (int d = 0; d < D_MODEL; d += 4) {
        float4 xv = *reinterpret_cast<const float4*>(xr + d);
        #pragma unroll
        for (int e = 0; e < NE; ++e) {
            acc[e] += xv.x * s_wg[(d + 0) * NE + e];
            acc[e] += xv.y * s_wg[(d + 1) * NE + e];
            acc[e] += xv.z * s_wg[(d + 2) * NE + e];
            acc[e] += xv.w * s_wg[(d + 3) * NE + e];
        }
    }
    int i0 = 0;
    #pragma unroll
    for (int e = 1; e < NE; ++e) if (acc[e] > acc[i0]) i0 = e;
    int i1 = (i0 == 0) ? 1 : 0;
    #pragma unroll
    for (int e = 0; e < NE; ++e) if (e != i0 && acc[e] > acc[i1]) i1 = e;
    float e1 = __expf(acc[i1] - acc[i0]);
    float inv = 1.0f / (1.0f + e1);
    float w0 = inv, w1 = e1 * inv;

    int p0 = atomicAdd(&cnt[i0], 1);
    tok_ids[i0 * MAXTOK + p0] = t;  tok_w[i0 * MAXTOK + p0] = w0;
    tokexp[t * 2 + 0] = i0 * MAXTOK + p0;
    int p1 = atomicAdd(&cnt[i1], 1);
    tok_ids[i1 * MAXTOK + p1] = t;  tok_w[i1 * MAXTOK + p1] = w1;
    tokexp[t * 2 + 1] = i1 * MAXTOK + p1;
}

// ---------------- scan: 256-aligned per-expert row offsets ----------------
__global__ void scan256_kernel(const int* __restrict__ cnt, int* __restrict__ off) {
    if (threadIdx.x == 0) {
        int acc = 0;
        for (int e = 0; e < NE; ++e) { off[e] = acc; acc += ((cnt[e] + 255) & ~255); }
        off[NE] = acc;
    }
}

// ---------------- gather: x rows -> compact bf16 Xg (k-half swizzled) ----------------
__global__ __launch_bounds__(256) void gather_kernel(
    const float* __restrict__ x, const int* __restrict__ cnt, const int* __restrict__ off,
    const int* __restrict__ tok_ids, const float* __restrict__ tok_w,
    ushort* __restrict__ Xg, int* __restrict__ rowtok, float* __restrict__ roww)
{
    int e = blockIdx.y;
    int npad = off[e + 1] - off[e];
    int r0 = blockIdx.x * 128;
    if (r0 >= npad) return;
    int n = cnt[e];
    int base = off[e];
    for (int idx = threadIdx.x; idx < 128 * 128; idx += 256) {
        int r = r0 + (idx >> 7);
        int s = idx & 127;           // 16B slot within row (8 bf16)
        int R = base + r;
        int tok = -1;
        float4 v0 = {0, 0, 0, 0}, v1 = {0, 0, 0, 0};
        if (r < n) {
            tok = tok_ids[e * MAXTOK + r];
            const float4* src = (const float4*)(x + (size_t)tok * D_MODEL + s * 8);
            v0 = src[0]; v1 = src[1];
        }
        ushort o[8];
        o[0] = f2b(v0.x); o[1] = f2b(v0.y); o[2] = f2b(v0.z); o[3] = f2b(v0.w);
        o[4] = f2b(v1.x); o[5] = f2b(v1.y); o[6] = f2b(v1.z); o[7] = f2b(v1.w);
        int c = s >> 3, sub = s & 7;
        *(uint4*)(Xg + (size_t)R * D_MODEL + c * 64 + swz_pos(sub, R)) = *(const uint4*)o;
        if (s == 0) {
            rowtok[R] = tok;
            roww[R] = (tok >= 0) ? tok_w[e * MAXTOK + r] : 0.0f;
        }
    }
}

// ---------------- weight transpose+convert: [e][K][N] f32 -> [e][N][K] bf16 swizzled ----------------
__global__ __launch_bounds__(256) void wconv_kernel(
    const float* __restrict__ src, ushort* __restrict__ dst, int K, int N)
{
    __shared__ float st[64][65];
    int e = blockIdx.z;
    int n0 = blockIdx.x * 64;
    int k0 = blockIdx.y * 64;
    const float* s = src + (size_t)e * K * N;
    ushort* d = dst + (size_t)e * N * K;
    for (int i = threadIdx.x; i < 4096; i += 256) {
        int kr = i >> 6, nc = i & 63;
        st[kr][nc] = s[(size_t)(k0 + kr) * N + n0 + nc];
    }
    __syncthreads();
    int c = k0 >> 6;
    #pragma unroll
    for (int it = 0; it < 2; ++it) {
        int v = threadIdx.x + it * 256;
        int nl = v >> 3, sub = v & 7;
        ushort o[8];
        #pragma unroll
        for (int j = 0; j < 8; ++j) o[j] = f2b(st[sub * 8 + j][nl]);
        *(uint4*)(d + (size_t)(n0 + nl) * K + c * 64 + swz_pos(sub, n0 + nl)) = *(const uint4*)o;
    }
}

// ================= 256x256 counted-vmcnt pipelined GEMM =================
// 8 waves (2M x 4N), per-wave 128x64. BK=64 split into 2 k-halves of 32.
// 4 phases per K-step: (kh, mh), 16 MFMA each. One 16KB stage-unit per phase
// into the other dbuf slot; vmcnt(4) every 2 phases (never drains to 0).
// LDS: A [2 slot][2 kh][256 row][32 col] ushort = 64KB, B same = 128KB.

#define STAGE_U(gbase, gstride, ktw, kh, slot, breg) { \
    _Pragma("unroll") \
    for (int l = 0; l < 2; ++l) { \
        int flat = l * 512 + tid; int row_ = flat >> 2, q_ = flat & 3; \
        __builtin_amdgcn_global_load_lds( \
            (const __attribute__((address_space(1))) void*)((gbase) + (size_t)row_ * (gstride) + (ktw) * 64 + (kh) * 32 + q_ * 8), \
            (__attribute__((address_space(3))) void*)(smem + (breg) + (slot) * 16384 + (kh) * 8192 + flat * 8), 16, 0, 0); \
    } }

#define PHASE(s, kh, mh, DO_B, STAGE_CODE, VMC) { \
    const ushort* As_ = smem + (s) * 16384 + (kh) * 8192; \
    const ushort* Bs_ = smem + 32768 + (s) * 16384 + (kh) * 8192; \
    if (DO_B) { \
        _Pragma("unroll") \
        for (int n = 0; n < 4; ++n) { \
            int br = wcn + n * 16; \
            int q = (jj + ((br >> 1) & 3)) & 3; \
            bfr[n] = *(const short8*)(Bs_ + br * 32 + q * 8); \
        } } \
    short8 afr[4]; \
    _Pragma("unroll") \
    for (int m = 0; m < 4; ++m) { \
        int ar = wrm + (mh) * 64 + m * 16; \
        int q = (jj + ((ar >> 1) & 3)) & 3; \
        afr[m] = *(const short8*)(As_ + ar * 32 + q * 8); \
    } \
    STAGE_CODE; \
    __builtin_amdgcn_s_barrier(); \
    asm volatile("s_waitcnt lgkmcnt(0)" ::: "memory"); \
    __builtin_amdgcn_s_setprio(1); \
    _Pragma("unroll") \
    for (int m = 0; m < 4; ++m) \
        _Pragma("unroll") \
        for (int n = 0; n < 4; ++n) \
            acc[(mh) * 4 + m][n] = __builtin_amdgcn_mfma_f32_16x16x32_bf16(afr[m], bfr[n], acc[(mh) * 4 + m][n], 0, 0, 0); \
    __builtin_amdgcn_s_setprio(0); \
    if (VMC) asm volatile("s_waitcnt vmcnt(4)" ::: "memory"); \
    __builtin_amdgcn_s_barrier(); \
}

template<bool GELU>
__global__ __launch_bounds__(512, 2) void gemm8(
    const ushort* __restrict__ Aall, const ushort* __restrict__ Ball,
    const float* __restrict__ bias, const int* __restrict__ off,
    ushort* __restrict__ Hout, float* __restrict__ Yout)
{
    __shared__ ushort smem[65536];  // 128 KB
    constexpr int LDA  = GELU ? D_MODEL : D_FF;   // A row stride
    constexpr int NDIM = GELU ? D_FF : D_MODEL;   // output cols
    constexpr int NKS  = GELU ? 1 : 2;            // K-splits
    constexpr int NK   = LDA / (64 * NKS);        // K-steps per block: 16 or 32
    constexpr int NT   = NDIM >> 8;
    constexpr int PER  = NT * NKS;

    int wid = xcd_swz(blockIdx.x, MAXMT * PER);
    int mt = wid / PER; int rr = wid % PER;
    int nt = rr % NT;   int ks = rr / NT;
    int row0 = mt << 8;
    if (row0 >= off[NE]) return;
    int e = 0;
    #pragma unroll
    for (int i = 1; i < NE; ++i) if (off[i] <= row0) e = i;
    int nb0 = nt << 8;
    int ktbase = ks * NK;

    int tid = threadIdx.x;
    int lane = tid & 63, wave = tid >> 6;
    int wr = wave >> 2, wc = wave & 3;
    int jj = lane >> 4;
    int wrm = wr * 128 + (lane & 15);
    int wcn = wc * 64 + (lane & 15);

    const ushort* Ab = Aall + (size_t)row0 * LDA;
    const ushort* Bb = Ball + ((size_t)e * NDIM + nb0) * LDA;

    f32x4 acc[8][4];
    #pragma unroll
    for (int m = 0; m < 8; ++m)
        #pragma unroll
        for (int n = 0; n < 4; ++n)
            acc[m][n] = (f32x4){0.f, 0.f, 0.f, 0.f};

    // prologue: stage K-step 0 fully into slot 0 (A-k0, B-k0, A-k1, B-k1)
    STAGE_U(Ab, LDA, ktbase, 0, 0, 0);
    STAGE_U(Bb, LDA, ktbase, 0, 0, 32768);
    STAGE_U(Ab, LDA, ktbase, 1, 0, 0);
    STAGE_U(Bb, LDA, ktbase, 1, 0, 32768);
    asm volatile("s_waitcnt vmcnt(4)" ::: "memory");  // k0 halves landed; k1 halves in flight
    __builtin_amdgcn_s_barrier();

    short8 bfr[4];
    for (int kt = 0; kt < NK; ++kt) {
        int s = kt & 1, sn = s ^ 1;
        int ktn = (kt + 1 == NK) ? 0 : kt + 1;    // wrap: harmless re-stage, uniform counts
        int kta = ktbase + ktn;
        // ph1: (kh0, mh0); stage A(kt+1, kh0)
        PHASE(s, 0, 0, 1, STAGE_U(Ab, LDA, kta, 0, sn, 0), 0);
        // ph2: (kh0, mh1); stage B(kt+1, kh0); vmcnt(4) -> confirms this kt's k1 halves
        PHASE(s, 0, 1, 0, STAGE_U(Bb, LDA, kta, 0, sn, 32768), 1);
        // ph3: (kh1, mh0); stage A(kt+1, kh1)
        PHASE(s, 1, 0, 1, STAGE_U(Ab, LDA, kta, 1, sn, 0), 0);
        // ph4: (kh1, mh1); stage B(kt+1, kh1); vmcnt(4) -> confirms kt+1's k0 halves
        PHASE(s, 1, 1, 0, STAGE_U(Bb, LDA, kta, 1, sn, 32768), 1);
    }
    asm volatile("s_waitcnt vmcnt(0)" ::: "memory");
    __syncthreads();

    if (GELU) {
        // epilogue: gelu -> LDS bounce (global-swizzled row layout) -> coalesced 16B stores
        const float* be = bias + (size_t)e * NDIM + nb0;
        #pragma unroll
        for (int n = 0; n < 4; ++n) {
            int cl = wc * 64 + n * 16 + (lane & 15);
            float bv = be[cl];
            int c4 = cl >> 6, sub = (cl >> 3) & 7, el = cl & 7;
            #pragma unroll
            for (int m = 0; m < 8; ++m) {
                int rb = wr * 128 + m * 16 + (lane >> 4) * 4;
                #pragma unroll
                for (int qq = 0; qq < 4; ++qq) {
                    int row = rb + qq;
                    float v = gelu_f(acc[m][n][qq] + bv);
                    smem[row * 256 + c4 * 64 + swz_pos(sub, row) + el] = f2b(v);
                }
            }
        }
        __syncthreads();
        #pragma unroll
        for (int it = 0; it < 16; ++it) {
            int flat = it * 512 + tid;          // 8192 x 16B
            int row = flat >> 5, g = flat & 31;
            *(uint4*)(Hout + (size_t)(row0 + row) * NDIM + nb0 + g * 8) = *(const uint4*)(smem + flat * 8);
        }
    } else {
        const float* be = bias + (size_t)e * NDIM + nb0;
        float* Yb = Yout + (size_t)ks * MAXROWS * NDIM;
        #pragma unroll
        for (int n = 0; n < 4; ++n) {
            int cl = wc * 64 + n * 16 + (lane & 15);
            float bv = (ks == 0) ? be[cl] : 0.0f;
            #pragma unroll
            for (int m = 0; m < 8; ++m) {
                int rb = wr * 128 + m * 16 + (lane >> 4) * 4;
                #pragma unroll
                for (int qq = 0; qq < 4; ++qq)
                    Yb[(size_t)(row0 + rb + qq) * NDIM + nb0 + cl] = acc[m][n][qq] + bv;
            }
        }
    }
}

// combine: out[t] = sum_k w_k * sum_s Y_s[R_k]
__global__ __launch_bounds__(256) void combine_kernel(
    const float* __restrict__ Y, const int* __restrict__ off,
    const int* __restrict__ tokexp, const float* __restrict__ tok_w,
    float* __restrict__ out, int nks)
{
    int t = blockIdx.x;
    int pos0 = tokexp[2 * t], pos1 = tokexp[2 * t + 1];
    int e0 = pos0 >> 12, p0 = pos0 & (MAXTOK - 1);
    int e1 = pos1 >> 12, p1 = pos1 & (MAXTOK - 1);
    size_t R0 = off[e0] + p0, R1 = off[e1] + p1;
    float w0 = tok_w[pos0], w1 = tok_w[pos1];
    int c = threadIdx.x * 4;
    float y0x = 0, y0y = 0, y0z = 0, y0w = 0;
    float y1x = 0, y1y = 0, y1z = 0, y1w = 0;
    for (int s = 0; s < nks; ++s) {
        const float* Ys = Y + (size_t)s * MAXROWS * D_MODEL;
        float4 a = *(const float4*)(Ys + R0 * D_MODEL + c);
        float4 b = *(const float4*)(Ys + R1 * D_MODEL + c);
        y0x += a.x; y0y += a.y; y0z += a.z; y0w += a.w;
        y1x += b.x; y1y += b.y; y1z += b.z; y1w += b.w;
    }
    float4 o;
    o.x = w0 * y0x + w1 * y1x;
    o.y = w0 * y0y + w1 * y1y;
    o.z = w0 * y0z + w1 * y1z;
    o.w = w0 * y0w + w1 * y1w;
    *(float4*)(out + (size_t)t * D_MODEL + c) = o;
}

// ================= legacy fp32 fallback =================
#define TM      32
#define FFC     128
#define KSTEP   64

__global__ __launch_bounds__(512) void ffn_kernel(
    const float* __restrict__ x,
    const float* __restrict__ W1, const float* __restrict__ b1,
    const float* __restrict__ W2, const float* __restrict__ b2,
    const int* __restrict__ cnt, const int* __restrict__ tok_ids, const float* __restrict__ tok_w,
    float* __restrict__ out)
{
    int e = blockIdx.y;
    int n = cnt[e];
    int t0 = blockIdx.x * TM;
    if (t0 >= n) return;
    int tid = threadIdx.x;

    __shared__ int   s_tok[TM];
    __shared__ float s_w[TM];
    __shared__ float s_x[TM][KSTEP];
    __shared__ float s_w1[KSTEP][FFC];
    __shared__ float s_h[TM][FFC];

    if (tid < TM) {
        int idx = t0 + tid;
        s_tok[tid] = (idx < n) ? tok_ids[e * MAXTOK + idx] : -1;
        s_w[tid]   = (idx < n) ? tok_w[e * MAXTOK + idx] : 0.0f;
    }
    __syncthreads();

    float acc[TM][2];
    #pragma unroll
    for (int i = 0; i < TM; ++i) { acc[i][0] = 0.0f; acc[i][1] = 0.0f; }

    const float* W1e = W1 + (size_t)e * D_MODEL * D_FF;
    const float* W2e = W2 + (size_t)e * D_FF * D_MODEL;
    const float* b1e = b1 + (size_t)e * D_FF;

    int ffl = (tid & 63) * 2;
    int g   = tid >> 6;

    int fb0 = blockIdx.z * (D_FF / 2);
    for (int fb = fb0; fb < fb0 + D_FF / 2; fb += FFC) {
        float bv0 = b1e[fb + ffl], bv1 = b1e[fb + ffl + 1];
        float hacc[4][2];
        #pragma unroll
        for (int j = 0; j < 4; ++j) { hacc[j][0] = bv0; hacc[j][1] = bv1; }

        for (int kb = 0; kb < D_MODEL; kb += KSTEP) {
            #pragma unroll
            for (int r = 0; r < 4; ++r) {
                int i = tid + 512 * r;
                int row = i >> 6, col = i & 63;
                int tok = s_tok[row];
                s_x[row][col] = (tok >= 0) ? x[(size_t)tok * D_MODEL + kb + col] : 0.0f;
            }
            #pragma unroll
            for (int r = 0; r < 16; ++r) {
                int i = tid + 512 * r;
                int row = i >> 7, col = i & 127;
                s_w1[row][col] = W1e[(size_t)(kb + row) * D_FF + fb + col];
            }
            __syncthreads();
            #pragma unroll 8
            for (int kk = 0; kk < KSTEP; ++kk) {
                float2 wv = *reinterpret_cast<const float2*>(&s_w1[kk][ffl]);
                #pragma unroll
                for (int j = 0; j < 4; ++j) {
                    float xv = s_x[g * 4 + j][kk];
                    hacc[j][0] += xv * wv.x;
                    hacc[j][1] += xv * wv.y;
                }
            }
            __syncthreads();
        }
        #pragma unroll
        for (int j = 0; j < 4; ++j) {
            #pragma unroll
            for (int p = 0; p < 2; ++p) {
                float v = hacc[j][p];
                v = 0.5f * v * (1.0f + erff(v * 0.70710678118654752f));
                s_h[g * 4 + j][ffl + p] = v;
            }
        }
        __syncthreads();
        for (int ff = 0; ff < FFC; ++ff) {
            const float* w2row = W2e + (size_t)(fb + ff) * D_MODEL;
            float wc0 = w2row[tid], wc1 = w2row[tid + 512];
            #pragma unroll
            for (int tt = 0; tt < TM; ++tt) {
                float hv = s_h[tt][ff];
                acc[tt][0] += hv * wc0;
                acc[tt][1] += hv * wc1;
            }
        }
        __syncthreads();
    }

    float bc0 = b2[(size_t)e * D_MODEL + tid];
    float bc1 = b2[(size_t)e * D_MODEL + tid + 512];
    if (blockIdx.z != 0) { bc0 = 0.0f; bc1 = 0.0f; }
    #pragma unroll
    for (int tt = 0; tt < TM; ++tt) {
        int tok = s_tok[tt];
        if (tok >= 0) {
            float w = s_w[tt];
            atomicAdd(&out[(size_t)tok * D_MODEL + tid],       w * (acc[tt][0] + bc0));
            atomicAdd(&out[(size_t)tok * D_MODEL + tid + 512], w * (acc[tt][1] + bc1));
        }
    }
}

extern "C" void kernel_launch(void* const* d_in, const int* in_sizes, int n_in,
                              void* d_out, int out_size, void* d_ws, size_t ws_size,
                              hipStream_t stream) {
    const float* x  = (const float*)d_in[0];
    const float* Wg = (const float*)d_in[1];
    const float* bg = (const float*)d_in[2];
    const float* W1 = (const float*)d_in[3];
    const float* b1 = (const float*)d_in[4];
    const float* W2 = (const float*)d_in[5];
    const float* b2 = (const float*)d_in[6];
    float* out = (float*)d_out;

    char* ws = (char*)d_ws;
    int*    cnt     = (int*)(ws + WS_CNT);
    int*    offp    = (int*)(ws + WS_OFFA);
    int*    tok_ids = (int*)(ws + WS_TOKIDS);
    float*  tok_w   = (float*)(ws + WS_TOKW);
    int*    rowtok  = (int*)(ws + WS_ROWTOK);
    float*  roww    = (float*)(ws + WS_ROWW);
    int*    tokexp  = (int*)(ws + WS_TOKEXP);

    hipMemsetAsync(cnt, 0, NE * sizeof(int), stream);
    gating_kernel<<<NTOK / 256, 256, 0, stream>>>(x, Wg, bg, cnt, tok_ids, tok_w, tokexp);

    if (ws_size >= WS_NEED_A) {
        ushort* Hb  = (ushort*)(ws + WS_H);
        ushort* W1T = (ushort*)(ws + WS_W1T);
        ushort* Xg  = (ushort*)(ws + WS_XG);
        ushort* W2T = (ushort*)(ws + WS_W2T);
        float*  Y   = (float*)(ws + WS_W1T);   // aliases dead W1T+Xg after gemm1
        const int nks = 2;

        scan256_kernel<<<1, 64, 0, stream>>>(cnt, offp);
        wconv_kernel<<<dim3(D_FF / 64, D_MODEL / 64, NE), 256, 0, stream>>>(W1, W1T, D_MODEL, D_FF);
        wconv_kernel<<<dim3(D_MODEL / 64, D_FF / 64, NE), 256, 0, stream>>>(W2, W2T, D_FF, D_MODEL);
        gather_kernel<<<dim3(32, NE), 256, 0, stream>>>(x, cnt, offp, tok_ids, tok_w, Xg, rowtok, roww);
        gemm8<true><<<MAXMT * 16, 512, 0, stream>>>(Xg, W1T, b1, offp, Hb, nullptr);
        gemm8<false><<<MAXMT * 8, 512, 0, stream>>>(Hb, W2T, b2, offp, nullptr, Y);
        combine_kernel<<<NTOK, 256, 0, stream>>>(Y, offp, tokexp, tok_w, out, nks);
    } else {
        hipMemsetAsync(out, 0, (size_t)out_size * sizeof(float), stream);
        dim3 grid(MAXTOK / TM, NE, 2);
        ffn_kernel<<<grid, 512, 0, stream>>>(x, W1, b1, W2, b2, cnt, tok_ids, tok_w, out);
    }
}